// Round 10
// baseline (274.311 us; speedup 1.0000x reference)
//
#include <hip/hip_runtime.h>
#include <math.h>

#define R    116
#define R2   (116*116)
#define G    128
#define NN   (R*G)      // 14848 nodes
#define HID  64
#define EDIM 5
#define INCH 116
#define EMBD 16

__device__ __forceinline__ float waveReduceSum(float v) {
#pragma unroll
    for (int m = 32; m >= 1; m >>= 1) v += __shfl_xor(v, m, 64);
    return v;
}

// ---------------- edge-attr transpose: eat[g][j][i][e] = ea[g][i][j][e] -------
__global__ __launch_bounds__(256) void k_etr(
    const float* __restrict__ ea, float* __restrict__ eat) {
    int b = blockIdx.x;
    int g = b >> 4;
    int t = b & 15;
    int i0 = (t >> 2) << 5, j0 = (t & 3) << 5;
    int ni = min(32, R - i0), nj = min(32, R - j0);
    __shared__ float tile[32][165];
    const float* src = ea + ((size_t)(g*R + i0)*R + j0)*EDIM;
    int tot = ni * nj * EDIM;
    for (int idx = threadIdx.x; idx < tot; idx += 256) {
        int ii = idx / (nj*EDIM);
        int rem = idx - ii*(nj*EDIM);
        tile[ii][rem] = src[(size_t)ii*R*EDIM + rem];
    }
    __syncthreads();
    float* dst = eat + ((size_t)(g*R + j0)*R + i0)*EDIM;
    int tot2 = nj * ni * EDIM;
    for (int idx = threadIdx.x; idx < tot2; idx += 256) {
        int jj = idx / (ni*EDIM);
        int rem = idx - jj*(ni*EDIM);     // ii*5 + e
        int ii = rem / EDIM, e = rem - ii*EDIM;
        dst[(size_t)jj*R*EDIM + rem] = tile[ii][jj*EDIM + e];
    }
}

// ---------------- prepack GAT per-channel tables + We@att dots ----------------
__global__ __launch_bounds__(64) void k_prep(
    const float* __restrict__ We, const float* __restrict__ att,
    float* __restrict__ wepack, float* __restrict__ was2) {
    int l = blockIdx.x, c = threadIdx.x;
    const float* Wl = We + l*EDIM*HID;
    const float* al = att + l*HID;
    float g0=Wl[c], g1=Wl[64+c], g2=Wl[128+c], g3=Wl[192+c], g4=Wl[256+c];
    float at = al[c];
    float* wp = wepack + l*HID*8 + c*8;
    wp[0]=g0; wp[1]=g1; wp[2]=g2; wp[3]=g3; wp[4]=g4; wp[5]=at;
    wp[6]=0.f; wp[7]=0.f;
    float p0 = waveReduceSum(g0*at);
    float p1 = waveReduceSum(g1*at);
    float p2 = waveReduceSum(g2*at);
    float p3 = waveReduceSum(g3*at);
    float p4 = waveReduceSum(g4*at);
    if (c == 0) {
        float* ws = was2 + l*8;
        ws[0]=p0; ws[1]=p1; ws[2]=p2; ws[3]=p3; ws[4]=p4;
    }
}

// ---------------- encode: h = relu([x, emb[gid]] @ W + b), 4 nodes/block ------
__global__ __launch_bounds__(256) void k_encode(
    const float* __restrict__ x, const float* __restrict__ emb,
    const int* __restrict__ group_ids,
    const float* __restrict__ W, const float* __restrict__ bvec,
    float* __restrict__ h) {
    int w = threadIdx.x >> 6, lane = threadIdx.x & 63;
    int n = blockIdx.x*4 + w;
    __shared__ float xin[4][136];
    for (int idx = lane; idx < INCH; idx += 64) xin[w][idx] = x[(size_t)n*INCH + idx];
    if (lane < EMBD) xin[w][INCH + lane] = emb[group_ids[n]*EMBD + lane];
    float acc = bvec[lane];
#pragma unroll
    for (int k = 0; k < INCH + EMBD; k += 4) {
        float4 q = *(const float4*)&xin[w][k];
        acc = fmaf(q.x, W[(k  )*HID + lane], acc);
        acc = fmaf(q.y, W[(k+1)*HID + lane], acc);
        acc = fmaf(q.z, W[(k+2)*HID + lane], acc);
        acc = fmaf(q.w, W[(k+3)*HID + lane], acc);
    }
    h[(size_t)n*HID + lane] = fmaxf(acc, 0.f);
}

// ---------------- batchnorm stats (two-stage, deterministic) ----------------
__global__ __launch_bounds__(256) void k_stats_partial(
    const float* __restrict__ h, float* __restrict__ partials) {
    int b = blockIdx.x;
    int tid = threadIdx.x;
    int c = tid & 63, r0 = tid >> 6;
    float s = 0.f, s2 = 0.f;
    int row0 = b*64;
#pragma unroll
    for (int k = 0; k < 16; ++k) {
        float v = h[(size_t)(row0 + r0 + 4*k)*HID + c];
        s += v; s2 += v*v;
    }
    __shared__ float ls[256], l2[256];
    ls[tid] = s; l2[tid] = s2;
    __syncthreads();
    if (tid < 64) {
        s  = ls[tid] + ls[tid+64] + ls[tid+128] + ls[tid+192];
        s2 = l2[tid] + l2[tid+64] + l2[tid+128] + l2[tid+192];
        partials[b*128 + tid]      = s;
        partials[b*128 + 64 + tid] = s2;
    }
}

__global__ __launch_bounds__(64) void k_stats_final(
    const float* __restrict__ partials, const float* __restrict__ gam,
    const float* __restrict__ bet, float* __restrict__ stats) {
    int c = threadIdx.x;
    float s = 0.f, s2 = 0.f;
    for (int b = 0; b < NN/64; ++b) {
        s  += partials[b*128 + c];
        s2 += partials[b*128 + 64 + c];
    }
    float mu  = s / (float)NN;
    float var = s2 / (float)NN - mu*mu;
    float rs  = rsqrtf(var + 1e-5f);
    float sc  = rs * gam[c];
    stats[c]      = sc;
    stats[64 + c] = bet[c] - mu*sc;
}

// ------- GINE: 8 waves x 2 dsts, SCALAR edge strips, full occupancy ----------
__global__ __launch_bounds__(512) void k_gine(
    const float* __restrict__ h, const float* __restrict__ stats,
    const float* __restrict__ ea,
    const float* __restrict__ We, const float* __restrict__ be,
    const float* __restrict__ W1, const float* __restrict__ b1,
    const float* __restrict__ W2, const float* __restrict__ b2,
    float* __restrict__ hout) {
    int b = blockIdx.x;
    int g = b & (G-1), chunk = b >> 7;     // 8 chunks x 16 dsts
    int tid = threadIdx.x, w = tid >> 6, lane = tid & 63;
    int j0 = min(chunk*16 + w*2, R - 2);   // clamp: overlaps write identical values
    __shared__ float hs[R][64];
    __shared__ float t1s[8][68];
    size_t hbase = (size_t)g*R*HID;
    float scv = stats[lane], shv = stats[64 + lane];
    for (int idx = tid; idx < R*HID; idx += 512)     // idx&63 == lane
        hs[idx>>6][lane] = fmaf(h[hbase + idx], scv, shv);
    float w0=We[lane], w1v=We[64+lane], w2v=We[128+lane],
          w3v=We[192+lane], w4v=We[256+lane], bec=be[lane];
    __syncthreads();

    float acc0 = 0.f, acc1 = 0.f;
    int sbase = __builtin_amdgcn_readfirstlane((g*R*R + j0)*EDIM);
    for (int i = 0; i < R; ++i) {
        float hv = hs[i][lane];
        const float* sp = ea + sbase + i*(R*EDIM);   // uniform -> scalar loads
        float e0 = bec, e1 = bec;
        e0 = fmaf(sp[0], w0,  e0); e1 = fmaf(sp[5], w0,  e1);
        e0 = fmaf(sp[1], w1v, e0); e1 = fmaf(sp[6], w1v, e1);
        e0 = fmaf(sp[2], w2v, e0); e1 = fmaf(sp[7], w2v, e1);
        e0 = fmaf(sp[3], w3v, e0); e1 = fmaf(sp[8], w3v, e1);
        e0 = fmaf(sp[4], w4v, e0); e1 = fmaf(sp[9], w4v, e1);
        acc0 += fmaxf(hv + e0, 0.f);
        acc1 += fmaxf(hv + e1, 0.f);
    }
    float accs[2] = {acc0, acc1};
#pragma unroll
    for (int j = 0; j < 2; ++j) {
        int jd = j0 + j;
        float h1 = hs[jd][lane] + accs[j];
        t1s[w][lane] = h1;                 // same-wave in-order LDS
        float a1 = b1[lane];
#pragma unroll
        for (int k = 0; k < HID; k += 4) {
            float4 tq = *(const float4*)&t1s[w][k];
            a1 = fmaf(tq.x, W1[(k  )*HID + lane], a1);
            a1 = fmaf(tq.y, W1[(k+1)*HID + lane], a1);
            a1 = fmaf(tq.z, W1[(k+2)*HID + lane], a1);
            a1 = fmaf(tq.w, W1[(k+3)*HID + lane], a1);
        }
        t1s[w][lane] = fmaxf(a1, 0.f);
        float a2 = b2[lane];
#pragma unroll
        for (int k = 0; k < HID; k += 4) {
            float4 tq = *(const float4*)&t1s[w][k];
            a2 = fmaf(tq.x, W2[(k  )*HID + lane], a2);
            a2 = fmaf(tq.y, W2[(k+1)*HID + lane], a2);
            a2 = fmaf(tq.z, W2[(k+2)*HID + lane], a2);
            a2 = fmaf(tq.w, W2[(k+3)*HID + lane], a2);
        }
        hout[hbase + (size_t)jd*HID + lane] = fmaxf(a2, 0.f);
    }
}

// ---------------- GAT: xl/xr projections + att-dot precompute ----------------
__global__ __launch_bounds__(256) void k_xlxr(
    const float* __restrict__ h,
    const float* __restrict__ Wl, const float* __restrict__ bl,
    const float* __restrict__ Wr, const float* __restrict__ br,
    const float* __restrict__ att,
    float* __restrict__ xl, float* __restrict__ xr,
    float* __restrict__ axl, float* __restrict__ axr) {
    int w = threadIdx.x >> 6, lane = threadIdx.x & 63;
    int n = blockIdx.x*4 + w;
    __shared__ float hr[4][68];
    hr[w][lane] = h[(size_t)n*HID + lane];
    float aL = bl[lane], aR = br[lane];
#pragma unroll
    for (int k = 0; k < HID; k += 4) {
        float4 q = *(const float4*)&hr[w][k];
        aL = fmaf(q.x, Wl[(k  )*HID + lane], aL);
        aR = fmaf(q.x, Wr[(k  )*HID + lane], aR);
        aL = fmaf(q.y, Wl[(k+1)*HID + lane], aL);
        aR = fmaf(q.y, Wr[(k+1)*HID + lane], aR);
        aL = fmaf(q.z, Wl[(k+2)*HID + lane], aL);
        aR = fmaf(q.z, Wr[(k+2)*HID + lane], aR);
        aL = fmaf(q.w, Wl[(k+3)*HID + lane], aL);
        aR = fmaf(q.w, Wr[(k+3)*HID + lane], aR);
    }
    xl[(size_t)n*HID + lane] = aL;
    xr[(size_t)n*HID + lane] = aR;
    float at = att[lane];
    float pL = waveReduceSum(aL * at);
    float pR = waveReduceSum(aR * at);
    if (lane == 0) { axl[n] = pL; axr[n] = pR; }
}

// ------- GAT: 8 waves/block at full occupancy, scalar wepack/xr loads --------
__global__ __launch_bounds__(512) void k_gat(
    const float* __restrict__ xl, const float* __restrict__ xr,
    const float* __restrict__ axlg, const float* __restrict__ axrg,
    const float* __restrict__ eat, const float* __restrict__ wepack,
    const float* __restrict__ wasg, const float* __restrict__ bias,
    float* __restrict__ hout) {
    int b = blockIdx.x;
    int g = b & (G-1), chunk = b >> 7;     // 8 chunks x 15 dsts
    int j0 = chunk*15, jcnt = min(15, R - j0);
    int tid = threadIdx.x, w = tid >> 6, lane = tid & 63;
    __shared__ float xls[R][66];           // stride 66: 8B-aligned rows
    __shared__ float ps[8][120];
    size_t hbase = (size_t)g*R*HID;
    for (int idx = tid; idx < R*HID; idx += 512)
        xls[idx>>6][idx&63] = xl[hbase + idx];
    float biasv = bias[lane];
    float wasv0 = wasg[0], wasv1 = wasg[1], wasv2 = wasg[2],
          wasv3 = wasg[3], wasv4 = wasg[4];
    bool vB = lane < (R - 64);
    int rb = vB ? (64 + lane) : lane;      // clamped B-row
    float axA = axlg[g*R + lane];
    float axB = axlg[g*R + rb];
    __syncthreads();

    for (int jj = w; jj < jcnt; jj += 8) {
        int j = j0 + jj;
        const float* colp = eat + (size_t)(g*R + j)*R*EDIM;
        float eA[5], eB[5];
#pragma unroll
        for (int e = 0; e < 5; ++e) {
            eA[e] = colp[lane*EDIM + e];
            eB[e] = colp[rb*EDIM + e];
        }
        const float* xrp = xr + hbase + (size_t)j*HID;   // uniform -> scalar
        float axrj = axrg[g*R + j];                      // uniform
        float accA = 0.f, accB = 0.f;
#pragma unroll 4
        for (int c = 0; c < HID; c += 2) {
            float2 xA2 = *(const float2*)&xls[lane][c];
            float2 xB2 = *(const float2*)&xls[rb][c];
            {
                const float* wp = wepack + c*8;          // uniform -> scalar
                float u = xrp[c];
                float zA = xA2.x + u;
                zA = fmaf(eA[0],wp[0],zA); zA = fmaf(eA[1],wp[1],zA);
                zA = fmaf(eA[2],wp[2],zA); zA = fmaf(eA[3],wp[3],zA);
                zA = fmaf(eA[4],wp[4],zA);
                accA = fmaf(__builtin_fabsf(zA), wp[5], accA);
                float zB = xB2.x + u;
                zB = fmaf(eB[0],wp[0],zB); zB = fmaf(eB[1],wp[1],zB);
                zB = fmaf(eB[2],wp[2],zB); zB = fmaf(eB[3],wp[3],zB);
                zB = fmaf(eB[4],wp[4],zB);
                accB = fmaf(__builtin_fabsf(zB), wp[5], accB);
            }
            {
                const float* wp = wepack + (c+1)*8;
                float u = xrp[c+1];
                float zA = xA2.y + u;
                zA = fmaf(eA[0],wp[0],zA); zA = fmaf(eA[1],wp[1],zA);
                zA = fmaf(eA[2],wp[2],zA); zA = fmaf(eA[3],wp[3],zA);
                zA = fmaf(eA[4],wp[4],zA);
                accA = fmaf(__builtin_fabsf(zA), wp[5], accA);
                float zB = xB2.y + u;
                zB = fmaf(eB[0],wp[0],zB); zB = fmaf(eB[1],wp[1],zB);
                zB = fmaf(eB[2],wp[2],zB); zB = fmaf(eB[3],wp[3],zB);
                zB = fmaf(eB[4],wp[4],zB);
                accB = fmaf(__builtin_fabsf(zB), wp[5], accB);
            }
        }
        // linear part: L = axl + axr + ea . (We@att)
        float LA = axA + axrj, LB = axB + axrj;
        LA = fmaf(eA[0],wasv0,LA); LA = fmaf(eA[1],wasv1,LA);
        LA = fmaf(eA[2],wasv2,LA); LA = fmaf(eA[3],wasv3,LA);
        LA = fmaf(eA[4],wasv4,LA);
        LB = fmaf(eB[0],wasv0,LB); LB = fmaf(eB[1],wasv1,LB);
        LB = fmaf(eB[2],wasv2,LB); LB = fmaf(eB[3],wasv3,LB);
        LB = fmaf(eB[4],wasv4,LB);
        // lrelu(z,0.2) = 0.6z + 0.4|z| => score = 0.6*L + 0.4*acc
        float sA = fmaf(0.4f, accA, 0.6f*LA);
        float sB = vB ? fmaf(0.4f, accB, 0.6f*LB) : -1e30f;
        float m = fmaxf(sA, sB);
#pragma unroll
        for (int msk = 32; msk >= 1; msk >>= 1) m = fmaxf(m, __shfl_xor(m, msk, 64));
        float eAx = __expf(sA - m);
        float eBx = vB ? __expf(sB - m) : 0.f;
        float s = eAx + eBx;
#pragma unroll
        for (int msk = 32; msk >= 1; msk >>= 1) s += __shfl_xor(s, msk, 64);
        float inv = 1.f / (s + 1e-16f);
        ps[w][lane] = eAx * inv;
        if (vB) ps[w][64 + lane] = eBx * inv;
        // same-wave produce->consume
        float o = 0.f;
#pragma unroll 4
        for (int i = 0; i < R; i += 4) {
            float4 p4 = *(const float4*)&ps[w][i];
            o = fmaf(p4.x, xls[i  ][lane], o);
            o = fmaf(p4.y, xls[i+1][lane], o);
            o = fmaf(p4.z, xls[i+2][lane], o);
            o = fmaf(p4.w, xls[i+3][lane], o);
        }
        hout[hbase + (size_t)j*HID + lane] = fmaxf(o + biasv, 0.f);
    }
}

// ---------------- pooling ----------------
__global__ __launch_bounds__(256) void k_pool_score(
    const float* __restrict__ h, const float* __restrict__ W1,
    const float* __restrict__ b1, const float* __restrict__ w2,
    float* __restrict__ scores) {
    int w = threadIdx.x >> 6, lane = threadIdx.x & 63;
    int n = blockIdx.x*4 + w;
    __shared__ float hr[4][68];
    hr[w][lane] = h[(size_t)n*HID + lane];
    float acc = b1[lane];
#pragma unroll
    for (int k = 0; k < HID; k += 4) {
        float4 q = *(const float4*)&hr[w][k];
        acc = fmaf(q.x, W1[(k  )*HID + lane], acc);
        acc = fmaf(q.y, W1[(k+1)*HID + lane], acc);
        acc = fmaf(q.z, W1[(k+2)*HID + lane], acc);
        acc = fmaf(q.w, W1[(k+3)*HID + lane], acc);
    }
    float p = tanhf(acc) * w2[lane];
    p = waveReduceSum(p);
    if (lane == 0) scores[n] = p;
}

__global__ __launch_bounds__(1024) void k_pool_reduce(
    const float* __restrict__ scores, float* __restrict__ ms) {
    __shared__ float red[1024];
    int tid = threadIdx.x;
    float m = -1e30f;
    for (int i = tid; i < NN; i += 1024) m = fmaxf(m, scores[i]);
    red[tid] = m;
    __syncthreads();
    for (int s = 512; s > 0; s >>= 1) {
        if (tid < s) red[tid] = fmaxf(red[tid], red[tid+s]);
        __syncthreads();
    }
    float mx = red[0];
    __syncthreads();
    float sum = 0.f;
    for (int i = tid; i < NN; i += 1024) sum += __expf(scores[i] - mx);
    red[tid] = sum;
    __syncthreads();
    for (int s = 512; s > 0; s >>= 1) {
        if (tid < s) red[tid] += red[tid+s];
        __syncthreads();
    }
    if (tid == 0) { ms[0] = mx; ms[1] = red[0]; }
}

__global__ __launch_bounds__(64) void k_pool_final(
    const float* __restrict__ h, const float* __restrict__ scores,
    const float* __restrict__ ms,
    const float* __restrict__ lin1W, const float* __restrict__ lin1b,
    const float* __restrict__ lin2W, const float* __restrict__ lin2b,
    float* __restrict__ out) {
    int g = blockIdx.x, c = threadIdx.x;
    float mx = ms[0], inv = 1.f / ms[1];
    float pc = 0.f;
    int nb = g*R;
    for (int r = 0; r < R; ++r) {
        float wv = __expf(scores[nb + r] - mx) * inv;
        pc = fmaf(h[(size_t)(nb + r)*HID + c], wv, pc);
    }
    __shared__ float pl[HID];
    __shared__ float t[INCH];
    pl[c] = pc;
    __syncthreads();
    for (int k = c; k < INCH; k += 64) {
        float acc = lin1b[k];
#pragma unroll 8
        for (int q = 0; q < HID; ++q) acc = fmaf(pl[q], lin1W[q*INCH + k], acc);
        t[k] = fmaxf(acc, 0.f);
    }
    __syncthreads();
    if (c < 2) {
        float o = lin2b[c];
        for (int k = 0; k < INCH; ++k) o = fmaf(t[k], lin2W[k*2 + c], o);
        out[g*2 + c] = o;
    }
}

extern "C" void kernel_launch(void* const* d_in, const int* in_sizes, int n_in,
                              void* d_out, int out_size, void* d_ws, size_t ws_size,
                              hipStream_t stream) {
    (void)in_sizes; (void)n_in; (void)out_size; (void)ws_size;
    const float* x        = (const float*)d_in[0];
    const float* edge_attr= (const float*)d_in[1];
    const float* emb      = (const float*)d_in[2];
    const float* enc_W    = (const float*)d_in[3];
    const float* enc_b    = (const float*)d_in[4];
    const float* bn_g     = (const float*)d_in[5];
    const float* bn_b     = (const float*)d_in[6];
    const float* gine_We  = (const float*)d_in[7];
    const float* gine_be  = (const float*)d_in[8];
    const float* gine_W1  = (const float*)d_in[9];
    const float* gine_b1  = (const float*)d_in[10];
    const float* gine_W2  = (const float*)d_in[11];
    const float* gine_b2  = (const float*)d_in[12];
    const float* gat_Wl   = (const float*)d_in[13];
    const float* gat_bl   = (const float*)d_in[14];
    const float* gat_Wr   = (const float*)d_in[15];
    const float* gat_br   = (const float*)d_in[16];
    const float* gat_att  = (const float*)d_in[17];
    const float* gat_We   = (const float*)d_in[18];
    const float* gat_bias = (const float*)d_in[19];
    const float* pool_W1  = (const float*)d_in[20];
    const float* pool_b1  = (const float*)d_in[21];
    const float* pool_w2  = (const float*)d_in[22];
    const float* lin1_W   = (const float*)d_in[23];
    const float* lin1_b   = (const float*)d_in[24];
    const float* lin2_W   = (const float*)d_in[25];
    const float* lin2_b   = (const float*)d_in[26];
    const int*   group_ids= (const int*)d_in[29];
    float* out = (float*)d_out;

    float* w = (float*)d_ws;
    float* eat      = w;                            // R2*G*EDIM
    float* hA       = eat + (size_t)R2*G*EDIM;      // NN*HID
    float* hB       = hA + (size_t)NN*HID;
    float* xlb      = hB + (size_t)NN*HID;
    float* xrb      = xlb + (size_t)NN*HID;
    float* axl      = xrb + (size_t)NN*HID;         // NN
    float* axr      = axl + NN;                     // NN
    float* scores   = axr + NN;                     // NN
    float* partials = scores + NN;                  // 232*128
    float* stats    = partials + (NN/64)*128;       // 128
    float* pms      = stats + 128;                  // 2
    float* wepack   = pms + 2;                      // 2*64*8
    float* was2     = wepack + 2*HID*8;             // 2*8

    k_etr<<<G*16, 256, 0, stream>>>(edge_attr, eat);
    k_prep<<<2, 64, 0, stream>>>(gat_We, gat_att, wepack, was2);
    k_encode<<<NN/4, 256, 0, stream>>>(x, emb, group_ids, enc_W, enc_b, hA);
    k_stats_partial<<<NN/64, 256, 0, stream>>>(hA, partials);
    k_stats_final<<<1, 64, 0, stream>>>(partials, bn_g, bn_b, stats);
    k_gine<<<G*8, 512, 0, stream>>>(hA, stats, edge_attr, gine_We, gine_be,
                                    gine_W1, gine_b1, gine_W2, gine_b2, hB);
    // GAT layer 0: hB -> hA
    k_xlxr<<<NN/4, 256, 0, stream>>>(hB, gat_Wl, gat_bl, gat_Wr, gat_br,
                                     gat_att, xlb, xrb, axl, axr);
    k_gat<<<G*8, 512, 0, stream>>>(xlb, xrb, axl, axr, eat, wepack,
                                   was2, gat_bias, hA);
    // GAT layer 1: hA -> hB
    k_xlxr<<<NN/4, 256, 0, stream>>>(hA, gat_Wl + HID*HID, gat_bl + HID,
                                     gat_Wr + HID*HID, gat_br + HID,
                                     gat_att + HID, xlb, xrb, axl, axr);
    k_gat<<<G*8, 512, 0, stream>>>(xlb, xrb, axl, axr, eat, wepack + HID*8,
                                   was2 + 8, gat_bias + HID, hB);
    // pooling + head
    k_pool_score<<<NN/4, 256, 0, stream>>>(hB, pool_W1, pool_b1, pool_w2, scores);
    k_pool_reduce<<<1, 1024, 0, stream>>>(scores, pms);
    k_pool_final<<<G, 64, 0, stream>>>(hB, scores, pms, lin1_W, lin1_b,
                                       lin2_W, lin2_b, out);
}

// Round 11
// 268.579 us; speedup vs baseline: 1.0213x; 1.0213x over previous
//
#include <hip/hip_runtime.h>
#include <math.h>

#define R    116
#define R2   (116*116)
#define G    128
#define NN   (R*G)      // 14848 nodes
#define HID  64
#define EDIM 5
#define INCH 116
#define EMBD 16

__device__ __forceinline__ float waveReduceSum(float v) {
#pragma unroll
    for (int m = 32; m >= 1; m >>= 1) v += __shfl_xor(v, m, 64);
    return v;
}

__device__ __forceinline__ float rlane(float v, int i) {
    return __int_as_float(__builtin_amdgcn_readlane(__float_as_int(v), i));
}

// ---------------- edge-attr transpose: eat[g][j][i][e] = ea[g][i][j][e] -------
__global__ __launch_bounds__(256) void k_etr(
    const float* __restrict__ ea, float* __restrict__ eat) {
    int b = blockIdx.x;
    int g = b >> 4;
    int t = b & 15;
    int i0 = (t >> 2) << 5, j0 = (t & 3) << 5;
    int ni = min(32, R - i0), nj = min(32, R - j0);
    __shared__ float tile[32][165];
    const float* src = ea + ((size_t)(g*R + i0)*R + j0)*EDIM;
    int tot = ni * nj * EDIM;
    for (int idx = threadIdx.x; idx < tot; idx += 256) {
        int ii = idx / (nj*EDIM);
        int rem = idx - ii*(nj*EDIM);
        tile[ii][rem] = src[(size_t)ii*R*EDIM + rem];
    }
    __syncthreads();
    float* dst = eat + ((size_t)(g*R + j0)*R + i0)*EDIM;
    int tot2 = nj * ni * EDIM;
    for (int idx = threadIdx.x; idx < tot2; idx += 256) {
        int jj = idx / (ni*EDIM);
        int rem = idx - jj*(ni*EDIM);     // ii*5 + e
        int ii = rem / EDIM, e = rem - ii*EDIM;
        dst[(size_t)jj*R*EDIM + rem] = tile[ii][jj*EDIM + e];
    }
}

// ---------------- prepack GAT per-channel tables + We@att dots ----------------
__global__ __launch_bounds__(64) void k_prep(
    const float* __restrict__ We, const float* __restrict__ att,
    float* __restrict__ wepack, float* __restrict__ was2) {
    int l = blockIdx.x, c = threadIdx.x;
    const float* Wl = We + l*EDIM*HID;
    const float* al = att + l*HID;
    float g0=Wl[c], g1=Wl[64+c], g2=Wl[128+c], g3=Wl[192+c], g4=Wl[256+c];
    float at = al[c];
    float* wp = wepack + l*HID*8 + c*8;
    wp[0]=g0; wp[1]=g1; wp[2]=g2; wp[3]=g3; wp[4]=g4; wp[5]=at;
    wp[6]=0.f; wp[7]=0.f;
    float p0 = waveReduceSum(g0*at);
    float p1 = waveReduceSum(g1*at);
    float p2 = waveReduceSum(g2*at);
    float p3 = waveReduceSum(g3*at);
    float p4 = waveReduceSum(g4*at);
    if (c == 0) {
        float* ws = was2 + l*8;
        ws[0]=p0; ws[1]=p1; ws[2]=p2; ws[3]=p3; ws[4]=p4;
    }
}

// ---------------- encode: h = relu([x, emb[gid]] @ W + b), 4 nodes/block ------
__global__ __launch_bounds__(256) void k_encode(
    const float* __restrict__ x, const float* __restrict__ emb,
    const int* __restrict__ group_ids,
    const float* __restrict__ W, const float* __restrict__ bvec,
    float* __restrict__ h) {
    int w = threadIdx.x >> 6, lane = threadIdx.x & 63;
    int n = blockIdx.x*4 + w;
    __shared__ float xin[4][136];
    for (int idx = lane; idx < INCH; idx += 64) xin[w][idx] = x[(size_t)n*INCH + idx];
    if (lane < EMBD) xin[w][INCH + lane] = emb[group_ids[n]*EMBD + lane];
    float acc = bvec[lane];
#pragma unroll
    for (int k = 0; k < INCH + EMBD; k += 4) {
        float4 q = *(const float4*)&xin[w][k];
        acc = fmaf(q.x, W[(k  )*HID + lane], acc);
        acc = fmaf(q.y, W[(k+1)*HID + lane], acc);
        acc = fmaf(q.z, W[(k+2)*HID + lane], acc);
        acc = fmaf(q.w, W[(k+3)*HID + lane], acc);
    }
    h[(size_t)n*HID + lane] = fmaxf(acc, 0.f);
}

// ---------------- batchnorm stats (two-stage, deterministic) ----------------
__global__ __launch_bounds__(256) void k_stats_partial(
    const float* __restrict__ h, float* __restrict__ partials) {
    int b = blockIdx.x;
    int tid = threadIdx.x;
    int c = tid & 63, r0 = tid >> 6;
    float s = 0.f, s2 = 0.f;
    int row0 = b*64;
#pragma unroll
    for (int k = 0; k < 16; ++k) {
        float v = h[(size_t)(row0 + r0 + 4*k)*HID + c];
        s += v; s2 += v*v;
    }
    __shared__ float ls[256], l2[256];
    ls[tid] = s; l2[tid] = s2;
    __syncthreads();
    if (tid < 64) {
        s  = ls[tid] + ls[tid+64] + ls[tid+128] + ls[tid+192];
        s2 = l2[tid] + l2[tid+64] + l2[tid+128] + l2[tid+192];
        partials[b*128 + tid]      = s;
        partials[b*128 + 64 + tid] = s2;
    }
}

__global__ __launch_bounds__(64) void k_stats_final(
    const float* __restrict__ partials, const float* __restrict__ gam,
    const float* __restrict__ bet, float* __restrict__ stats) {
    int c = threadIdx.x;
    float s = 0.f, s2 = 0.f;
    for (int b = 0; b < NN/64; ++b) {
        s  += partials[b*128 + c];
        s2 += partials[b*128 + 64 + c];
    }
    float mu  = s / (float)NN;
    float var = s2 / (float)NN - mu*mu;
    float rs  = rsqrtf(var + 1e-5f);
    float sc  = rs * gam[c];
    stats[c]      = sc;
    stats[64 + c] = bet[c] - mu*sc;
}

// ------- GINE: wave per dst; per-lane edge strips + readlane broadcast -------
__global__ __launch_bounds__(256) void k_gine(
    const float* __restrict__ h, const float* __restrict__ stats,
    const float* __restrict__ eat,
    const float* __restrict__ We, const float* __restrict__ be,
    const float* __restrict__ W1, const float* __restrict__ b1,
    const float* __restrict__ W2, const float* __restrict__ b2,
    float* __restrict__ hout) {
    int b = blockIdx.x;
    int g = b & (G-1), chunk = b >> 7;     // grid G*29; chunk 0..28
    int tid = threadIdx.x, w = tid >> 6, lane = tid & 63;
    int j = chunk*4 + w;                   // exact cover of 116 dsts
    __shared__ float hs[R][64];
    __shared__ float t1s[4][68];
    size_t hbase = (size_t)g*R*HID;
    float scv = stats[lane], shv = stats[64 + lane];
    for (int idx = tid; idx < R*HID; idx += 256)
        hs[idx>>6][lane] = fmaf(h[hbase + idx], scv, shv);
    float w0=We[lane], w1v=We[64+lane], w2v=We[128+lane],
          w3v=We[192+lane], w4v=We[256+lane], bec=be[lane];
    // per-lane edge strips for this dst: batch A i=lane, batch B i=64+lane
    const float* col = eat + (size_t)(g*R + j)*R*EDIM;
    float4 fa; __builtin_memcpy(&fa, col + lane*EDIM, 16);
    float fa4 = col[lane*EDIM + 4];
    int ib = 64 + (lane < (R-64) ? lane : (R-64-1));
    float4 fb; __builtin_memcpy(&fb, col + ib*EDIM, 16);
    float fb4 = col[ib*EDIM + 4];
    __syncthreads();

    float agg = 0.f;
#pragma unroll 4
    for (int ii = 0; ii < 64; ++ii) {
        float s0 = rlane(fa.x, ii), s1 = rlane(fa.y, ii), s2 = rlane(fa.z, ii),
              s3 = rlane(fa.w, ii), s4 = rlane(fa4, ii);
        float ew = bec;
        ew = fmaf(s0, w0,  ew); ew = fmaf(s1, w1v, ew); ew = fmaf(s2, w2v, ew);
        ew = fmaf(s3, w3v, ew); ew = fmaf(s4, w4v, ew);
        agg += fmaxf(hs[ii][lane] + ew, 0.f);
    }
#pragma unroll 4
    for (int ii = 0; ii < R-64; ++ii) {
        float s0 = rlane(fb.x, ii), s1 = rlane(fb.y, ii), s2 = rlane(fb.z, ii),
              s3 = rlane(fb.w, ii), s4 = rlane(fb4, ii);
        float ew = bec;
        ew = fmaf(s0, w0,  ew); ew = fmaf(s1, w1v, ew); ew = fmaf(s2, w2v, ew);
        ew = fmaf(s3, w3v, ew); ew = fmaf(s4, w4v, ew);
        agg += fmaxf(hs[64+ii][lane] + ew, 0.f);
    }
    float h1 = hs[j][lane] + agg;
    t1s[w][lane] = h1;                     // same-wave in-order LDS
    float a1 = b1[lane];
#pragma unroll
    for (int k = 0; k < HID; k += 4) {
        float4 tq = *(const float4*)&t1s[w][k];
        a1 = fmaf(tq.x, W1[(k  )*HID + lane], a1);
        a1 = fmaf(tq.y, W1[(k+1)*HID + lane], a1);
        a1 = fmaf(tq.z, W1[(k+2)*HID + lane], a1);
        a1 = fmaf(tq.w, W1[(k+3)*HID + lane], a1);
    }
    t1s[w][lane] = fmaxf(a1, 0.f);
    float a2 = b2[lane];
#pragma unroll
    for (int k = 0; k < HID; k += 4) {
        float4 tq = *(const float4*)&t1s[w][k];
        a2 = fmaf(tq.x, W2[(k  )*HID + lane], a2);
        a2 = fmaf(tq.y, W2[(k+1)*HID + lane], a2);
        a2 = fmaf(tq.z, W2[(k+2)*HID + lane], a2);
        a2 = fmaf(tq.w, W2[(k+3)*HID + lane], a2);
    }
    hout[hbase + (size_t)j*HID + lane] = fmaxf(a2, 0.f);
}

// ---------------- GAT: xl/xr projections + att-dot precompute ----------------
__global__ __launch_bounds__(256) void k_xlxr(
    const float* __restrict__ h,
    const float* __restrict__ Wl, const float* __restrict__ bl,
    const float* __restrict__ Wr, const float* __restrict__ br,
    const float* __restrict__ att,
    float* __restrict__ xl, float* __restrict__ xr,
    float* __restrict__ axl, float* __restrict__ axr) {
    int w = threadIdx.x >> 6, lane = threadIdx.x & 63;
    int n = blockIdx.x*4 + w;
    __shared__ float hr[4][68];
    hr[w][lane] = h[(size_t)n*HID + lane];
    float aL = bl[lane], aR = br[lane];
#pragma unroll
    for (int k = 0; k < HID; k += 4) {
        float4 q = *(const float4*)&hr[w][k];
        aL = fmaf(q.x, Wl[(k  )*HID + lane], aL);
        aR = fmaf(q.x, Wr[(k  )*HID + lane], aR);
        aL = fmaf(q.y, Wl[(k+1)*HID + lane], aL);
        aR = fmaf(q.y, Wr[(k+1)*HID + lane], aR);
        aL = fmaf(q.z, Wl[(k+2)*HID + lane], aL);
        aR = fmaf(q.z, Wr[(k+2)*HID + lane], aR);
        aL = fmaf(q.w, Wl[(k+3)*HID + lane], aL);
        aR = fmaf(q.w, Wr[(k+3)*HID + lane], aR);
    }
    xl[(size_t)n*HID + lane] = aL;
    xr[(size_t)n*HID + lane] = aR;
    float at = att[lane];
    float pL = waveReduceSum(aL * at);
    float pR = waveReduceSum(aR * at);
    if (lane == 0) { axl[n] = pL; axr[n] = pR; }
}

// ------- GAT: paired dsts, scalar wepack/xr, readlane-broadcast agg ----------
__global__ __launch_bounds__(256) void k_gat(
    const float* __restrict__ xl, const float* __restrict__ xr,
    const float* __restrict__ axlg, const float* __restrict__ axrg,
    const float* __restrict__ eat, const float* __restrict__ wepack,
    const float* __restrict__ wasg, const float* __restrict__ bias,
    float* __restrict__ hout) {
    int b = blockIdx.x;
    int g = b & (G-1), chunk = b >> 7;     // 8 chunks x 15 dsts
    int j0c = chunk*15, jcnt = min(15, R - j0c);
    int tid = threadIdx.x, w = tid >> 6, lane = tid & 63;
    __shared__ float xls[R][66];           // stride 66: 8B-aligned rows
    size_t hbase = (size_t)g*R*HID;
    for (int idx = tid; idx < R*HID; idx += 256)
        xls[idx>>6][idx&63] = xl[hbase + idx];
    float biasv = bias[lane];
    float wasv0 = wasg[0], wasv1 = wasg[1], wasv2 = wasg[2],
          wasv3 = wasg[3], wasv4 = wasg[4];
    bool vB = lane < (R - 64);
    int rb = vB ? (64 + lane) : lane;      // clamped B-row
    float axA = axlg[g*R + lane];
    float axB = axlg[g*R + rb];
    __syncthreads();

    for (int p = 0; p < 2; ++p) {          // pairs {w, w+4}, {w+8, w+12}
        int jj0 = w + 8*p, jj1 = w + 4 + 8*p;
        bool act0 = jj0 < jcnt, act1 = jj1 < jcnt;
        int j0 = j0c + (act0 ? jj0 : 0);
        int j1 = j0c + (act1 ? jj1 : 0);
        const float* c0 = eat + (size_t)(g*R + j0)*R*EDIM;
        const float* c1 = eat + (size_t)(g*R + j1)*R*EDIM;
        float e0A[5], e0B[5], e1A[5], e1B[5];
#pragma unroll
        for (int e = 0; e < 5; ++e) {
            e0A[e] = c0[lane*EDIM + e];  e0B[e] = c0[rb*EDIM + e];
            e1A[e] = c1[lane*EDIM + e];  e1B[e] = c1[rb*EDIM + e];
        }
        int xo0 = __builtin_amdgcn_readfirstlane(j0*HID);
        int xo1 = __builtin_amdgcn_readfirstlane(j1*HID);
        const float* xr0 = xr + hbase + xo0;
        const float* xr1 = xr + hbase + xo1;
        float axr0 = axrg[g*R + j0];
        float axr1 = axrg[g*R + j1];
        float acc0A=0.f, acc0B=0.f, acc1A=0.f, acc1B=0.f;
#pragma unroll 4
        for (int c = 0; c < HID; c += 2) {
            float2 xA2 = *(const float2*)&xls[lane][c];
            float2 xB2 = *(const float2*)&xls[rb][c];
            const float* wpa = wepack + c*8;             // uniform -> scalar
            const float* wpb = wepack + (c+1)*8;
            float u0a = xr0[c], u0b = xr0[c+1];          // uniform -> scalar
            float u1a = xr1[c], u1b = xr1[c+1];
            {   // channel c
                float zA = xA2.x + u0a;
                zA = fmaf(e0A[0],wpa[0],zA); zA = fmaf(e0A[1],wpa[1],zA);
                zA = fmaf(e0A[2],wpa[2],zA); zA = fmaf(e0A[3],wpa[3],zA);
                zA = fmaf(e0A[4],wpa[4],zA);
                acc0A = fmaf(__builtin_fabsf(zA), wpa[5], acc0A);
                float zB = xB2.x + u0a;
                zB = fmaf(e0B[0],wpa[0],zB); zB = fmaf(e0B[1],wpa[1],zB);
                zB = fmaf(e0B[2],wpa[2],zB); zB = fmaf(e0B[3],wpa[3],zB);
                zB = fmaf(e0B[4],wpa[4],zB);
                acc0B = fmaf(__builtin_fabsf(zB), wpa[5], acc0B);
                float yA = xA2.x + u1a;
                yA = fmaf(e1A[0],wpa[0],yA); yA = fmaf(e1A[1],wpa[1],yA);
                yA = fmaf(e1A[2],wpa[2],yA); yA = fmaf(e1A[3],wpa[3],yA);
                yA = fmaf(e1A[4],wpa[4],yA);
                acc1A = fmaf(__builtin_fabsf(yA), wpa[5], acc1A);
                float yB = xB2.x + u1a;
                yB = fmaf(e1B[0],wpa[0],yB); yB = fmaf(e1B[1],wpa[1],yB);
                yB = fmaf(e1B[2],wpa[2],yB); yB = fmaf(e1B[3],wpa[3],yB);
                yB = fmaf(e1B[4],wpa[4],yB);
                acc1B = fmaf(__builtin_fabsf(yB), wpa[5], acc1B);
            }
            {   // channel c+1
                float zA = xA2.y + u0b;
                zA = fmaf(e0A[0],wpb[0],zA); zA = fmaf(e0A[1],wpb[1],zA);
                zA = fmaf(e0A[2],wpb[2],zA); zA = fmaf(e0A[3],wpb[3],zA);
                zA = fmaf(e0A[4],wpb[4],zA);
                acc0A = fmaf(__builtin_fabsf(zA), wpb[5], acc0A);
                float zB = xB2.y + u0b;
                zB = fmaf(e0B[0],wpb[0],zB); zB = fmaf(e0B[1],wpb[1],zB);
                zB = fmaf(e0B[2],wpb[2],zB); zB = fmaf(e0B[3],wpb[3],zB);
                zB = fmaf(e0B[4],wpb[4],zB);
                acc0B = fmaf(__builtin_fabsf(zB), wpb[5], acc0B);
                float yA = xA2.y + u1b;
                yA = fmaf(e1A[0],wpb[0],yA); yA = fmaf(e1A[1],wpb[1],yA);
                yA = fmaf(e1A[2],wpb[2],yA); yA = fmaf(e1A[3],wpb[3],yA);
                yA = fmaf(e1A[4],wpb[4],yA);
                acc1A = fmaf(__builtin_fabsf(yA), wpb[5], acc1A);
                float yB = xB2.y + u1b;
                yB = fmaf(e1B[0],wpb[0],yB); yB = fmaf(e1B[1],wpb[1],yB);
                yB = fmaf(e1B[2],wpb[2],yB); yB = fmaf(e1B[3],wpb[3],yB);
                yB = fmaf(e1B[4],wpb[4],yB);
                acc1B = fmaf(__builtin_fabsf(yB), wpb[5], acc1B);
            }
        }
        // linear parts: L = axl + axr + ea . (We@att)
        float L0A = axA + axr0, L0B = axB + axr0;
        L0A = fmaf(e0A[0],wasv0,L0A); L0A = fmaf(e0A[1],wasv1,L0A);
        L0A = fmaf(e0A[2],wasv2,L0A); L0A = fmaf(e0A[3],wasv3,L0A);
        L0A = fmaf(e0A[4],wasv4,L0A);
        L0B = fmaf(e0B[0],wasv0,L0B); L0B = fmaf(e0B[1],wasv1,L0B);
        L0B = fmaf(e0B[2],wasv2,L0B); L0B = fmaf(e0B[3],wasv3,L0B);
        L0B = fmaf(e0B[4],wasv4,L0B);
        float L1A = axA + axr1, L1B = axB + axr1;
        L1A = fmaf(e1A[0],wasv0,L1A); L1A = fmaf(e1A[1],wasv1,L1A);
        L1A = fmaf(e1A[2],wasv2,L1A); L1A = fmaf(e1A[3],wasv3,L1A);
        L1A = fmaf(e1A[4],wasv4,L1A);
        L1B = fmaf(e1B[0],wasv0,L1B); L1B = fmaf(e1B[1],wasv1,L1B);
        L1B = fmaf(e1B[2],wasv2,L1B); L1B = fmaf(e1B[3],wasv3,L1B);
        L1B = fmaf(e1B[4],wasv4,L1B);
        // lrelu(z,0.2) = 0.6z + 0.4|z| => score = 0.6*L + 0.4*acc
        float s0A = fmaf(0.4f, acc0A, 0.6f*L0A);
        float s0B = vB ? fmaf(0.4f, acc0B, 0.6f*L0B) : -1e30f;
        float m0 = fmaxf(s0A, s0B);
#pragma unroll
        for (int k = 32; k >= 1; k >>= 1) m0 = fmaxf(m0, __shfl_xor(m0, k, 64));
        float x0A = __expf(s0A - m0);
        float x0B = vB ? __expf(s0B - m0) : 0.f;
        float sm0 = x0A + x0B;
#pragma unroll
        for (int k = 32; k >= 1; k >>= 1) sm0 += __shfl_xor(sm0, k, 64);
        float inv0 = 1.f / (sm0 + 1e-16f);
        float p0A = x0A * inv0, p0B = x0B * inv0;

        float s1A = fmaf(0.4f, acc1A, 0.6f*L1A);
        float s1B = vB ? fmaf(0.4f, acc1B, 0.6f*L1B) : -1e30f;
        float m1 = fmaxf(s1A, s1B);
#pragma unroll
        for (int k = 32; k >= 1; k >>= 1) m1 = fmaxf(m1, __shfl_xor(m1, k, 64));
        float x1A = __expf(s1A - m1);
        float x1B = vB ? __expf(s1B - m1) : 0.f;
        float sm1 = x1A + x1B;
#pragma unroll
        for (int k = 32; k >= 1; k >>= 1) sm1 += __shfl_xor(sm1, k, 64);
        float inv1 = 1.f / (sm1 + 1e-16f);
        float p1A = x1A * inv1, p1B = x1B * inv1;

        // paired aggregation: readlane broadcasts, shared xls reads
        float o0 = 0.f, o1 = 0.f;
#pragma unroll 8
        for (int i = 0; i < 64; ++i) {
            float xv = xls[i][lane];
            o0 = fmaf(rlane(p0A, i), xv, o0);
            o1 = fmaf(rlane(p1A, i), xv, o1);
        }
#pragma unroll 4
        for (int i = 0; i < R-64; ++i) {
            float xv = xls[64+i][lane];
            o0 = fmaf(rlane(p0B, i), xv, o0);
            o1 = fmaf(rlane(p1B, i), xv, o1);
        }
        if (act0) hout[hbase + (size_t)j0*HID + lane] = fmaxf(o0 + biasv, 0.f);
        if (act1) hout[hbase + (size_t)j1*HID + lane] = fmaxf(o1 + biasv, 0.f);
    }
}

// ---------------- pooling ----------------
__global__ __launch_bounds__(256) void k_pool_score(
    const float* __restrict__ h, const float* __restrict__ W1,
    const float* __restrict__ b1, const float* __restrict__ w2,
    float* __restrict__ scores) {
    int w = threadIdx.x >> 6, lane = threadIdx.x & 63;
    int n = blockIdx.x*4 + w;
    __shared__ float hr[4][68];
    hr[w][lane] = h[(size_t)n*HID + lane];
    float acc = b1[lane];
#pragma unroll
    for (int k = 0; k < HID; k += 4) {
        float4 q = *(const float4*)&hr[w][k];
        acc = fmaf(q.x, W1[(k  )*HID + lane], acc);
        acc = fmaf(q.y, W1[(k+1)*HID + lane], acc);
        acc = fmaf(q.z, W1[(k+2)*HID + lane], acc);
        acc = fmaf(q.w, W1[(k+3)*HID + lane], acc);
    }
    float p = tanhf(acc) * w2[lane];
    p = waveReduceSum(p);
    if (lane == 0) scores[n] = p;
}

__global__ __launch_bounds__(1024) void k_pool_reduce(
    const float* __restrict__ scores, float* __restrict__ ms) {
    __shared__ float red[1024];
    int tid = threadIdx.x;
    float m = -1e30f;
    for (int i = tid; i < NN; i += 1024) m = fmaxf(m, scores[i]);
    red[tid] = m;
    __syncthreads();
    for (int s = 512; s > 0; s >>= 1) {
        if (tid < s) red[tid] = fmaxf(red[tid], red[tid+s]);
        __syncthreads();
    }
    float mx = red[0];
    __syncthreads();
    float sum = 0.f;
    for (int i = tid; i < NN; i += 1024) sum += __expf(scores[i] - mx);
    red[tid] = sum;
    __syncthreads();
    for (int s = 512; s > 0; s >>= 1) {
        if (tid < s) red[tid] += red[tid+s];
        __syncthreads();
    }
    if (tid == 0) { ms[0] = mx; ms[1] = red[0]; }
}

__global__ __launch_bounds__(64) void k_pool_final(
    const float* __restrict__ h, const float* __restrict__ scores,
    const float* __restrict__ ms,
    const float* __restrict__ lin1W, const float* __restrict__ lin1b,
    const float* __restrict__ lin2W, const float* __restrict__ lin2b,
    float* __restrict__ out) {
    int g = blockIdx.x, c = threadIdx.x;
    float mx = ms[0], inv = 1.f / ms[1];
    float pc = 0.f;
    int nb = g*R;
    for (int r = 0; r < R; ++r) {
        float wv = __expf(scores[nb + r] - mx) * inv;
        pc = fmaf(h[(size_t)(nb + r)*HID + c], wv, pc);
    }
    __shared__ float pl[HID];
    __shared__ float t[INCH];
    pl[c] = pc;
    __syncthreads();
    for (int k = c; k < INCH; k += 64) {
        float acc = lin1b[k];
#pragma unroll 8
        for (int q = 0; q < HID; ++q) acc = fmaf(pl[q], lin1W[q*INCH + k], acc);
        t[k] = fmaxf(acc, 0.f);
    }
    __syncthreads();
    if (c < 2) {
        float o = lin2b[c];
        for (int k = 0; k < INCH; ++k) o = fmaf(t[k], lin2W[k*2 + c], o);
        out[g*2 + c] = o;
    }
}

extern "C" void kernel_launch(void* const* d_in, const int* in_sizes, int n_in,
                              void* d_out, int out_size, void* d_ws, size_t ws_size,
                              hipStream_t stream) {
    (void)in_sizes; (void)n_in; (void)out_size; (void)ws_size;
    const float* x        = (const float*)d_in[0];
    const float* edge_attr= (const float*)d_in[1];
    const float* emb      = (const float*)d_in[2];
    const float* enc_W    = (const float*)d_in[3];
    const float* enc_b    = (const float*)d_in[4];
    const float* bn_g     = (const float*)d_in[5];
    const float* bn_b     = (const float*)d_in[6];
    const float* gine_We  = (const float*)d_in[7];
    const float* gine_be  = (const float*)d_in[8];
    const float* gine_W1  = (const float*)d_in[9];
    const float* gine_b1  = (const float*)d_in[10];
    const float* gine_W2  = (const float*)d_in[11];
    const float* gine_b2  = (const float*)d_in[12];
    const float* gat_Wl   = (const float*)d_in[13];
    const float* gat_bl   = (const float*)d_in[14];
    const float* gat_Wr   = (const float*)d_in[15];
    const float* gat_br   = (const float*)d_in[16];
    const float* gat_att  = (const float*)d_in[17];
    const float* gat_We   = (const float*)d_in[18];
    const float* gat_bias = (const float*)d_in[19];
    const float* pool_W1  = (const float*)d_in[20];
    const float* pool_b1  = (const float*)d_in[21];
    const float* pool_w2  = (const float*)d_in[22];
    const float* lin1_W   = (const float*)d_in[23];
    const float* lin1_b   = (const float*)d_in[24];
    const float* lin2_W   = (const float*)d_in[25];
    const float* lin2_b   = (const float*)d_in[26];
    const int*   group_ids= (const int*)d_in[29];
    float* out = (float*)d_out;

    float* w = (float*)d_ws;
    float* eat      = w;                            // R2*G*EDIM
    float* hA       = eat + (size_t)R2*G*EDIM;      // NN*HID
    float* hB       = hA + (size_t)NN*HID;
    float* xlb      = hB + (size_t)NN*HID;
    float* xrb      = xlb + (size_t)NN*HID;
    float* axl      = xrb + (size_t)NN*HID;         // NN
    float* axr      = axl + NN;                     // NN
    float* scores   = axr + NN;                     // NN
    float* partials = scores + NN;                  // 232*128
    float* stats    = partials + (NN/64)*128;       // 128
    float* pms      = stats + 128;                  // 2
    float* wepack   = pms + 2;                      // 2*64*8
    float* was2     = wepack + 2*HID*8;             // 2*8

    k_etr<<<G*16, 256, 0, stream>>>(edge_attr, eat);
    k_prep<<<2, 64, 0, stream>>>(gat_We, gat_att, wepack, was2);
    k_encode<<<NN/4, 256, 0, stream>>>(x, emb, group_ids, enc_W, enc_b, hA);
    k_stats_partial<<<NN/64, 256, 0, stream>>>(hA, partials);
    k_stats_final<<<1, 64, 0, stream>>>(partials, bn_g, bn_b, stats);
    k_gine<<<G*29, 256, 0, stream>>>(hA, stats, eat, gine_We, gine_be,
                                     gine_W1, gine_b1, gine_W2, gine_b2, hB);
    // GAT layer 0: hB -> hA
    k_xlxr<<<NN/4, 256, 0, stream>>>(hB, gat_Wl, gat_bl, gat_Wr, gat_br,
                                     gat_att, xlb, xrb, axl, axr);
    k_gat<<<G*8, 256, 0, stream>>>(xlb, xrb, axl, axr, eat, wepack,
                                   was2, gat_bias, hA);
    // GAT layer 1: hA -> hB
    k_xlxr<<<NN/4, 256, 0, stream>>>(hA, gat_Wl + HID*HID, gat_bl + HID,
                                     gat_Wr + HID*HID, gat_br + HID,
                                     gat_att + HID, xlb, xrb, axl, axr);
    k_gat<<<G*8, 256, 0, stream>>>(xlb, xrb, axl, axr, eat, wepack + HID*8,
                                   was2 + 8, gat_bias + HID, hB);
    // pooling + head
    k_pool_score<<<NN/4, 256, 0, stream>>>(hB, pool_W1, pool_b1, pool_w2, scores);
    k_pool_reduce<<<1, 1024, 0, stream>>>(scores, pms);
    k_pool_final<<<G, 64, 0, stream>>>(hB, scores, pms, lin1_W, lin1_b,
                                       lin2_W, lin2_b, out);
}

// Round 12
// 258.613 us; speedup vs baseline: 1.0607x; 1.0385x over previous
//
#include <hip/hip_runtime.h>
#include <math.h>

#define R    116
#define R2   (116*116)
#define G    128
#define NN   (R*G)      // 14848 nodes
#define HID  64
#define EDIM 5
#define INCH 116
#define EMBD 16

__device__ __forceinline__ float waveReduceSum(float v) {
#pragma unroll
    for (int m = 32; m >= 1; m >>= 1) v += __shfl_xor(v, m, 64);
    return v;
}

__device__ __forceinline__ float rlane(float v, int i) {
    return __int_as_float(__builtin_amdgcn_readlane(__float_as_int(v), i));
}

// ---------------- edge-attr transpose: eat[g][j][i][e] = ea[g][i][j][e] -------
__global__ __launch_bounds__(256) void k_etr(
    const float* __restrict__ ea, float* __restrict__ eat) {
    int b = blockIdx.x;
    int g = b >> 4;
    int t = b & 15;
    int i0 = (t >> 2) << 5, j0 = (t & 3) << 5;
    int ni = min(32, R - i0), nj = min(32, R - j0);
    __shared__ float tile[32][165];
    const float* src = ea + ((size_t)(g*R + i0)*R + j0)*EDIM;
    int tot = ni * nj * EDIM;
    for (int idx = threadIdx.x; idx < tot; idx += 256) {
        int ii = idx / (nj*EDIM);
        int rem = idx - ii*(nj*EDIM);
        tile[ii][rem] = src[(size_t)ii*R*EDIM + rem];
    }
    __syncthreads();
    float* dst = eat + ((size_t)(g*R + j0)*R + i0)*EDIM;
    int tot2 = nj * ni * EDIM;
    for (int idx = threadIdx.x; idx < tot2; idx += 256) {
        int jj = idx / (ni*EDIM);
        int rem = idx - jj*(ni*EDIM);     // ii*5 + e
        int ii = rem / EDIM, e = rem - ii*EDIM;
        dst[(size_t)jj*R*EDIM + rem] = tile[ii][jj*EDIM + e];
    }
}

// ---------------- prepack GAT per-channel tables + We@att dots ----------------
__global__ __launch_bounds__(64) void k_prep(
    const float* __restrict__ We, const float* __restrict__ att,
    float* __restrict__ wepack, float* __restrict__ was2) {
    int l = blockIdx.x, c = threadIdx.x;
    const float* Wl = We + l*EDIM*HID;
    const float* al = att + l*HID;
    float g0=Wl[c], g1=Wl[64+c], g2=Wl[128+c], g3=Wl[192+c], g4=Wl[256+c];
    float at = al[c];
    float* wp = wepack + l*HID*8 + c*8;
    wp[0]=g0; wp[1]=g1; wp[2]=g2; wp[3]=g3; wp[4]=g4; wp[5]=at;
    wp[6]=0.f; wp[7]=0.f;
    float p0 = waveReduceSum(g0*at);
    float p1 = waveReduceSum(g1*at);
    float p2 = waveReduceSum(g2*at);
    float p3 = waveReduceSum(g3*at);
    float p4 = waveReduceSum(g4*at);
    if (c == 0) {
        float* ws = was2 + l*8;
        ws[0]=p0; ws[1]=p1; ws[2]=p2; ws[3]=p3; ws[4]=p4;
    }
}

// ---------------- encode: h = relu([x, emb[gid]] @ W + b), 4 nodes/block ------
__global__ __launch_bounds__(256) void k_encode(
    const float* __restrict__ x, const float* __restrict__ emb,
    const int* __restrict__ group_ids,
    const float* __restrict__ W, const float* __restrict__ bvec,
    float* __restrict__ h) {
    int w = threadIdx.x >> 6, lane = threadIdx.x & 63;
    int n = blockIdx.x*4 + w;
    __shared__ float xin[4][136];
    for (int idx = lane; idx < INCH; idx += 64) xin[w][idx] = x[(size_t)n*INCH + idx];
    if (lane < EMBD) xin[w][INCH + lane] = emb[group_ids[n]*EMBD + lane];
    float acc = bvec[lane];
#pragma unroll
    for (int k = 0; k < INCH + EMBD; k += 4) {
        float4 q = *(const float4*)&xin[w][k];
        acc = fmaf(q.x, W[(k  )*HID + lane], acc);
        acc = fmaf(q.y, W[(k+1)*HID + lane], acc);
        acc = fmaf(q.z, W[(k+2)*HID + lane], acc);
        acc = fmaf(q.w, W[(k+3)*HID + lane], acc);
    }
    h[(size_t)n*HID + lane] = fmaxf(acc, 0.f);
}

// ---------------- batchnorm stats (two-stage, deterministic) ----------------
__global__ __launch_bounds__(256) void k_stats_partial(
    const float* __restrict__ h, float* __restrict__ partials) {
    int b = blockIdx.x;
    int tid = threadIdx.x;
    int c = tid & 63, r0 = tid >> 6;
    float s = 0.f, s2 = 0.f;
    int row0 = b*64;
#pragma unroll
    for (int k = 0; k < 16; ++k) {
        float v = h[(size_t)(row0 + r0 + 4*k)*HID + c];
        s += v; s2 += v*v;
    }
    __shared__ float ls[256], l2[256];
    ls[tid] = s; l2[tid] = s2;
    __syncthreads();
    if (tid < 64) {
        s  = ls[tid] + ls[tid+64] + ls[tid+128] + ls[tid+192];
        s2 = l2[tid] + l2[tid+64] + l2[tid+128] + l2[tid+192];
        partials[b*128 + tid]      = s;
        partials[b*128 + 64 + tid] = s2;
    }
}

__global__ __launch_bounds__(64) void k_stats_final(
    const float* __restrict__ partials, const float* __restrict__ gam,
    const float* __restrict__ bet, float* __restrict__ stats) {
    int c = threadIdx.x;
    float s = 0.f, s2 = 0.f;
    for (int b = 0; b < NN/64; ++b) {
        s  += partials[b*128 + c];
        s2 += partials[b*128 + 64 + c];
    }
    float mu  = s / (float)NN;
    float var = s2 / (float)NN - mu*mu;
    float rs  = rsqrtf(var + 1e-5f);
    float sc  = rs * gam[c];
    stats[c]      = sc;
    stats[64 + c] = bet[c] - mu*sc;
}

// ------- GINE: wave per dst; edge col in LDS (uniform reads), h from L1 ------
__global__ __launch_bounds__(256) void k_gine(
    const float* __restrict__ h, const float* __restrict__ stats,
    const float* __restrict__ eat,
    const float* __restrict__ We, const float* __restrict__ be,
    const float* __restrict__ W1, const float* __restrict__ b1,
    const float* __restrict__ W2, const float* __restrict__ b2,
    float* __restrict__ hout) {
    int b = blockIdx.x;
    int g = b & (G-1), chunk = b >> 7;     // grid G*29; chunk 0..28
    int tid = threadIdx.x, w = tid >> 6, lane = tid & 63;
    int j = chunk*4 + w;                   // exact cover of 116 dsts
    __shared__ float eac[4][R*8];          // per-wave edge column, 8-padded
    __shared__ float t1s[4][68];
    size_t hbase = (size_t)g*R*HID;
    float scv = stats[lane], shv = stats[64 + lane];
    // stage edge column [R][5] -> [R][8] (per-wave buffer; no barrier needed)
    const float* col = eat + (size_t)(g*R + j)*R*EDIM;
    for (int idx = lane; idx < R*EDIM; idx += 64) {
        int i = idx / EDIM, e = idx - i*EDIM;
        eac[w][i*8 + e] = col[idx];
    }
    float w0=We[lane], w1v=We[64+lane], w2v=We[128+lane],
          w3v=We[192+lane], w4v=We[256+lane], bec=be[lane];
    const float* hg = h + hbase;
    float agg = 0.f;
#pragma unroll 4
    for (int i = 0; i < R; ++i) {
        float4 q = *(const float4*)&eac[w][i*8];     // uniform LDS broadcast
        float q4 = eac[w][i*8 + 4];
        float hv = fmaf(hg[(size_t)i*HID + lane], scv, shv);  // L1-hot global
        float ew = bec;
        ew = fmaf(q.x, w0,  ew); ew = fmaf(q.y, w1v, ew);
        ew = fmaf(q.z, w2v, ew); ew = fmaf(q.w, w3v, ew);
        ew = fmaf(q4,  w4v, ew);
        agg += fmaxf(hv + ew, 0.f);
    }
    float h1 = fmaf(hg[(size_t)j*HID + lane], scv, shv) + agg;
    t1s[w][lane] = h1;                     // same-wave in-order LDS
    float a1 = b1[lane];
#pragma unroll
    for (int k = 0; k < HID; k += 4) {
        float4 tq = *(const float4*)&t1s[w][k];
        a1 = fmaf(tq.x, W1[(k  )*HID + lane], a1);
        a1 = fmaf(tq.y, W1[(k+1)*HID + lane], a1);
        a1 = fmaf(tq.z, W1[(k+2)*HID + lane], a1);
        a1 = fmaf(tq.w, W1[(k+3)*HID + lane], a1);
    }
    t1s[w][lane] = fmaxf(a1, 0.f);
    float a2 = b2[lane];
#pragma unroll
    for (int k = 0; k < HID; k += 4) {
        float4 tq = *(const float4*)&t1s[w][k];
        a2 = fmaf(tq.x, W2[(k  )*HID + lane], a2);
        a2 = fmaf(tq.y, W2[(k+1)*HID + lane], a2);
        a2 = fmaf(tq.z, W2[(k+2)*HID + lane], a2);
        a2 = fmaf(tq.w, W2[(k+3)*HID + lane], a2);
    }
    hout[hbase + (size_t)j*HID + lane] = fmaxf(a2, 0.f);
}

// ---------------- GAT: xl/xr projections + att-dot precompute ----------------
__global__ __launch_bounds__(256) void k_xlxr(
    const float* __restrict__ h,
    const float* __restrict__ Wl, const float* __restrict__ bl,
    const float* __restrict__ Wr, const float* __restrict__ br,
    const float* __restrict__ att,
    float* __restrict__ xl, float* __restrict__ xr,
    float* __restrict__ axl, float* __restrict__ axr) {
    int w = threadIdx.x >> 6, lane = threadIdx.x & 63;
    int n = blockIdx.x*4 + w;
    __shared__ float hr[4][68];
    hr[w][lane] = h[(size_t)n*HID + lane];
    float aL = bl[lane], aR = br[lane];
#pragma unroll
    for (int k = 0; k < HID; k += 4) {
        float4 q = *(const float4*)&hr[w][k];
        aL = fmaf(q.x, Wl[(k  )*HID + lane], aL);
        aR = fmaf(q.x, Wr[(k  )*HID + lane], aR);
        aL = fmaf(q.y, Wl[(k+1)*HID + lane], aL);
        aR = fmaf(q.y, Wr[(k+1)*HID + lane], aR);
        aL = fmaf(q.z, Wl[(k+2)*HID + lane], aL);
        aR = fmaf(q.z, Wr[(k+2)*HID + lane], aR);
        aL = fmaf(q.w, Wl[(k+3)*HID + lane], aL);
        aR = fmaf(q.w, Wr[(k+3)*HID + lane], aR);
    }
    xl[(size_t)n*HID + lane] = aL;
    xr[(size_t)n*HID + lane] = aR;
    float at = att[lane];
    float pL = waveReduceSum(aL * at);
    float pR = waveReduceSum(aR * at);
    if (lane == 0) { axl[n] = pL; axr[n] = pR; }
}

// ------- GAT: paired dsts, scalar wepack/xr, readlane-broadcast agg ----------
__global__ __launch_bounds__(256) void k_gat(
    const float* __restrict__ xl, const float* __restrict__ xr,
    const float* __restrict__ axlg, const float* __restrict__ axrg,
    const float* __restrict__ eat, const float* __restrict__ wepack,
    const float* __restrict__ wasg, const float* __restrict__ bias,
    float* __restrict__ hout) {
    int b = blockIdx.x;
    int g = b & (G-1), chunk = b >> 7;     // 8 chunks x 15 dsts
    int j0c = chunk*15, jcnt = min(15, R - j0c);
    int tid = threadIdx.x, w = tid >> 6, lane = tid & 63;
    __shared__ float xls[R][66];           // stride 66: 8B-aligned rows
    size_t hbase = (size_t)g*R*HID;
    for (int idx = tid; idx < R*HID; idx += 256)
        xls[idx>>6][idx&63] = xl[hbase + idx];
    float biasv = bias[lane];
    float wasv0 = wasg[0], wasv1 = wasg[1], wasv2 = wasg[2],
          wasv3 = wasg[3], wasv4 = wasg[4];
    bool vB = lane < (R - 64);
    int rb = vB ? (64 + lane) : lane;      // clamped B-row
    float axA = axlg[g*R + lane];
    float axB = axlg[g*R + rb];
    __syncthreads();

    for (int p = 0; p < 2; ++p) {          // pairs {w, w+4}, {w+8, w+12}
        int jj0 = w + 8*p, jj1 = w + 4 + 8*p;
        bool act0 = jj0 < jcnt, act1 = jj1 < jcnt;
        int j0 = j0c + (act0 ? jj0 : 0);
        int j1 = j0c + (act1 ? jj1 : 0);
        const float* c0 = eat + (size_t)(g*R + j0)*R*EDIM;
        const float* c1 = eat + (size_t)(g*R + j1)*R*EDIM;
        float e0A[5], e0B[5], e1A[5], e1B[5];
#pragma unroll
        for (int e = 0; e < 5; ++e) {
            e0A[e] = c0[lane*EDIM + e];  e0B[e] = c0[rb*EDIM + e];
            e1A[e] = c1[lane*EDIM + e];  e1B[e] = c1[rb*EDIM + e];
        }
        int xo0 = __builtin_amdgcn_readfirstlane(j0*HID);
        int xo1 = __builtin_amdgcn_readfirstlane(j1*HID);
        const float* xr0 = xr + hbase + xo0;
        const float* xr1 = xr + hbase + xo1;
        float axr0 = axrg[g*R + j0];
        float axr1 = axrg[g*R + j1];
        float acc0A=0.f, acc0B=0.f, acc1A=0.f, acc1B=0.f;
#pragma unroll 4
        for (int c = 0; c < HID; c += 2) {
            float2 xA2 = *(const float2*)&xls[lane][c];
            float2 xB2 = *(const float2*)&xls[rb][c];
            const float* wpa = wepack + c*8;             // uniform -> scalar
            const float* wpb = wepack + (c+1)*8;
            float u0a = xr0[c], u0b = xr0[c+1];          // uniform -> scalar
            float u1a = xr1[c], u1b = xr1[c+1];
            {   // channel c
                float zA = xA2.x + u0a;
                zA = fmaf(e0A[0],wpa[0],zA); zA = fmaf(e0A[1],wpa[1],zA);
                zA = fmaf(e0A[2],wpa[2],zA); zA = fmaf(e0A[3],wpa[3],zA);
                zA = fmaf(e0A[4],wpa[4],zA);
                acc0A = fmaf(__builtin_fabsf(zA), wpa[5], acc0A);
                float zB = xB2.x + u0a;
                zB = fmaf(e0B[0],wpa[0],zB); zB = fmaf(e0B[1],wpa[1],zB);
                zB = fmaf(e0B[2],wpa[2],zB); zB = fmaf(e0B[3],wpa[3],zB);
                zB = fmaf(e0B[4],wpa[4],zB);
                acc0B = fmaf(__builtin_fabsf(zB), wpa[5], acc0B);
                float yA = xA2.x + u1a;
                yA = fmaf(e1A[0],wpa[0],yA); yA = fmaf(e1A[1],wpa[1],yA);
                yA = fmaf(e1A[2],wpa[2],yA); yA = fmaf(e1A[3],wpa[3],yA);
                yA = fmaf(e1A[4],wpa[4],yA);
                acc1A = fmaf(__builtin_fabsf(yA), wpa[5], acc1A);
                float yB = xB2.x + u1a;
                yB = fmaf(e1B[0],wpa[0],yB); yB = fmaf(e1B[1],wpa[1],yB);
                yB = fmaf(e1B[2],wpa[2],yB); yB = fmaf(e1B[3],wpa[3],yB);
                yB = fmaf(e1B[4],wpa[4],yB);
                acc1B = fmaf(__builtin_fabsf(yB), wpa[5], acc1B);
            }
            {   // channel c+1
                float zA = xA2.y + u0b;
                zA = fmaf(e0A[0],wpb[0],zA); zA = fmaf(e0A[1],wpb[1],zA);
                zA = fmaf(e0A[2],wpb[2],zA); zA = fmaf(e0A[3],wpb[3],zA);
                zA = fmaf(e0A[4],wpb[4],zA);
                acc0A = fmaf(__builtin_fabsf(zA), wpb[5], acc0A);
                float zB = xB2.y + u0b;
                zB = fmaf(e0B[0],wpb[0],zB); zB = fmaf(e0B[1],wpb[1],zB);
                zB = fmaf(e0B[2],wpb[2],zB); zB = fmaf(e0B[3],wpb[3],zB);
                zB = fmaf(e0B[4],wpb[4],zB);
                acc0B = fmaf(__builtin_fabsf(zB), wpb[5], acc0B);
                float yA = xA2.y + u1b;
                yA = fmaf(e1A[0],wpb[0],yA); yA = fmaf(e1A[1],wpb[1],yA);
                yA = fmaf(e1A[2],wpb[2],yA); yA = fmaf(e1A[3],wpb[3],yA);
                yA = fmaf(e1A[4],wpb[4],yA);
                acc1A = fmaf(__builtin_fabsf(yA), wpb[5], acc1A);
                float yB = xB2.y + u1b;
                yB = fmaf(e1B[0],wpb[0],yB); yB = fmaf(e1B[1],wpb[1],yB);
                yB = fmaf(e1B[2],wpb[2],yB); yB = fmaf(e1B[3],wpb[3],yB);
                yB = fmaf(e1B[4],wpb[4],yB);
                acc1B = fmaf(__builtin_fabsf(yB), wpb[5], acc1B);
            }
        }
        // linear parts: L = axl + axr + ea . (We@att)
        float L0A = axA + axr0, L0B = axB + axr0;
        L0A = fmaf(e0A[0],wasv0,L0A); L0A = fmaf(e0A[1],wasv1,L0A);
        L0A = fmaf(e0A[2],wasv2,L0A); L0A = fmaf(e0A[3],wasv3,L0A);
        L0A = fmaf(e0A[4],wasv4,L0A);
        L0B = fmaf(e0B[0],wasv0,L0B); L0B = fmaf(e0B[1],wasv1,L0B);
        L0B = fmaf(e0B[2],wasv2,L0B); L0B = fmaf(e0B[3],wasv3,L0B);
        L0B = fmaf(e0B[4],wasv4,L0B);
        float L1A = axA + axr1, L1B = axB + axr1;
        L1A = fmaf(e1A[0],wasv0,L1A); L1A = fmaf(e1A[1],wasv1,L1A);
        L1A = fmaf(e1A[2],wasv2,L1A); L1A = fmaf(e1A[3],wasv3,L1A);
        L1A = fmaf(e1A[4],wasv4,L1A);
        L1B = fmaf(e1B[0],wasv0,L1B); L1B = fmaf(e1B[1],wasv1,L1B);
        L1B = fmaf(e1B[2],wasv2,L1B); L1B = fmaf(e1B[3],wasv3,L1B);
        L1B = fmaf(e1B[4],wasv4,L1B);
        // lrelu(z,0.2) = 0.6z + 0.4|z| => score = 0.6*L + 0.4*acc
        float s0A = fmaf(0.4f, acc0A, 0.6f*L0A);
        float s0B = vB ? fmaf(0.4f, acc0B, 0.6f*L0B) : -1e30f;
        float m0 = fmaxf(s0A, s0B);
#pragma unroll
        for (int k = 32; k >= 1; k >>= 1) m0 = fmaxf(m0, __shfl_xor(m0, k, 64));
        float x0A = __expf(s0A - m0);
        float x0B = vB ? __expf(s0B - m0) : 0.f;
        float sm0 = x0A + x0B;
#pragma unroll
        for (int k = 32; k >= 1; k >>= 1) sm0 += __shfl_xor(sm0, k, 64);
        float inv0 = 1.f / (sm0 + 1e-16f);
        float p0A = x0A * inv0, p0B = x0B * inv0;

        float s1A = fmaf(0.4f, acc1A, 0.6f*L1A);
        float s1B = vB ? fmaf(0.4f, acc1B, 0.6f*L1B) : -1e30f;
        float m1 = fmaxf(s1A, s1B);
#pragma unroll
        for (int k = 32; k >= 1; k >>= 1) m1 = fmaxf(m1, __shfl_xor(m1, k, 64));
        float x1A = __expf(s1A - m1);
        float x1B = vB ? __expf(s1B - m1) : 0.f;
        float sm1 = x1A + x1B;
#pragma unroll
        for (int k = 32; k >= 1; k >>= 1) sm1 += __shfl_xor(sm1, k, 64);
        float inv1 = 1.f / (sm1 + 1e-16f);
        float p1A = x1A * inv1, p1B = x1B * inv1;

        // paired aggregation: readlane broadcasts, shared xls reads
        float o0 = 0.f, o1 = 0.f;
#pragma unroll 8
        for (int i = 0; i < 64; ++i) {
            float xv = xls[i][lane];
            o0 = fmaf(rlane(p0A, i), xv, o0);
            o1 = fmaf(rlane(p1A, i), xv, o1);
        }
#pragma unroll 4
        for (int i = 0; i < R-64; ++i) {
            float xv = xls[64+i][lane];
            o0 = fmaf(rlane(p0B, i), xv, o0);
            o1 = fmaf(rlane(p1B, i), xv, o1);
        }
        if (act0) hout[hbase + (size_t)j0*HID + lane] = fmaxf(o0 + biasv, 0.f);
        if (act1) hout[hbase + (size_t)j1*HID + lane] = fmaxf(o1 + biasv, 0.f);
    }
}

// ---------------- pooling ----------------
__global__ __launch_bounds__(256) void k_pool_score(
    const float* __restrict__ h, const float* __restrict__ W1,
    const float* __restrict__ b1, const float* __restrict__ w2,
    float* __restrict__ scores) {
    int w = threadIdx.x >> 6, lane = threadIdx.x & 63;
    int n = blockIdx.x*4 + w;
    __shared__ float hr[4][68];
    hr[w][lane] = h[(size_t)n*HID + lane];
    float acc = b1[lane];
#pragma unroll
    for (int k = 0; k < HID; k += 4) {
        float4 q = *(const float4*)&hr[w][k];
        acc = fmaf(q.x, W1[(k  )*HID + lane], acc);
        acc = fmaf(q.y, W1[(k+1)*HID + lane], acc);
        acc = fmaf(q.z, W1[(k+2)*HID + lane], acc);
        acc = fmaf(q.w, W1[(k+3)*HID + lane], acc);
    }
    float p = tanhf(acc) * w2[lane];
    p = waveReduceSum(p);
    if (lane == 0) scores[n] = p;
}

__global__ __launch_bounds__(1024) void k_pool_reduce(
    const float* __restrict__ scores, float* __restrict__ ms) {
    __shared__ float red[1024];
    int tid = threadIdx.x;
    float m = -1e30f;
    for (int i = tid; i < NN; i += 1024) m = fmaxf(m, scores[i]);
    red[tid] = m;
    __syncthreads();
    for (int s = 512; s > 0; s >>= 1) {
        if (tid < s) red[tid] = fmaxf(red[tid], red[tid+s]);
        __syncthreads();
    }
    float mx = red[0];
    __syncthreads();
    float sum = 0.f;
    for (int i = tid; i < NN; i += 1024) sum += __expf(scores[i] - mx);
    red[tid] = sum;
    __syncthreads();
    for (int s = 512; s > 0; s >>= 1) {
        if (tid < s) red[tid] += red[tid+s];
        __syncthreads();
    }
    if (tid == 0) { ms[0] = mx; ms[1] = red[0]; }
}

__global__ __launch_bounds__(64) void k_pool_final(
    const float* __restrict__ h, const float* __restrict__ scores,
    const float* __restrict__ ms,
    const float* __restrict__ lin1W, const float* __restrict__ lin1b,
    const float* __restrict__ lin2W, const float* __restrict__ lin2b,
    float* __restrict__ out) {
    int g = blockIdx.x, c = threadIdx.x;
    float mx = ms[0], inv = 1.f / ms[1];
    float pc = 0.f;
    int nb = g*R;
    for (int r = 0; r < R; ++r) {
        float wv = __expf(scores[nb + r] - mx) * inv;
        pc = fmaf(h[(size_t)(nb + r)*HID + c], wv, pc);
    }
    __shared__ float pl[HID];
    __shared__ float t[INCH];
    pl[c] = pc;
    __syncthreads();
    for (int k = c; k < INCH; k += 64) {
        float acc = lin1b[k];
#pragma unroll 8
        for (int q = 0; q < HID; ++q) acc = fmaf(pl[q], lin1W[q*INCH + k], acc);
        t[k] = fmaxf(acc, 0.f);
    }
    __syncthreads();
    if (c < 2) {
        float o = lin2b[c];
        for (int k = 0; k < INCH; ++k) o = fmaf(t[k], lin2W[k*2 + c], o);
        out[g*2 + c] = o;
    }
}

extern "C" void kernel_launch(void* const* d_in, const int* in_sizes, int n_in,
                              void* d_out, int out_size, void* d_ws, size_t ws_size,
                              hipStream_t stream) {
    (void)in_sizes; (void)n_in; (void)out_size; (void)ws_size;
    const float* x        = (const float*)d_in[0];
    const float* edge_attr= (const float*)d_in[1];
    const float* emb      = (const float*)d_in[2];
    const float* enc_W    = (const float*)d_in[3];
    const float* enc_b    = (const float*)d_in[4];
    const float* bn_g     = (const float*)d_in[5];
    const float* bn_b     = (const float*)d_in[6];
    const float* gine_We  = (const float*)d_in[7];
    const float* gine_be  = (const float*)d_in[8];
    const float* gine_W1  = (const float*)d_in[9];
    const float* gine_b1  = (const float*)d_in[10];
    const float* gine_W2  = (const float*)d_in[11];
    const float* gine_b2  = (const float*)d_in[12];
    const float* gat_Wl   = (const float*)d_in[13];
    const float* gat_bl   = (const float*)d_in[14];
    const float* gat_Wr   = (const float*)d_in[15];
    const float* gat_br   = (const float*)d_in[16];
    const float* gat_att  = (const float*)d_in[17];
    const float* gat_We   = (const float*)d_in[18];
    const float* gat_bias = (const float*)d_in[19];
    const float* pool_W1  = (const float*)d_in[20];
    const float* pool_b1  = (const float*)d_in[21];
    const float* pool_w2  = (const float*)d_in[22];
    const float* lin1_W   = (const float*)d_in[23];
    const float* lin1_b   = (const float*)d_in[24];
    const float* lin2_W   = (const float*)d_in[25];
    const float* lin2_b   = (const float*)d_in[26];
    const int*   group_ids= (const int*)d_in[29];
    float* out = (float*)d_out;

    float* w = (float*)d_ws;
    float* eat      = w;                            // R2*G*EDIM
    float* hA       = eat + (size_t)R2*G*EDIM;      // NN*HID
    float* hB       = hA + (size_t)NN*HID;
    float* xlb      = hB + (size_t)NN*HID;
    float* xrb      = xlb + (size_t)NN*HID;
    float* axl      = xrb + (size_t)NN*HID;         // NN
    float* axr      = axl + NN;                     // NN
    float* scores   = axr + NN;                     // NN
    float* partials = scores + NN;                  // 232*128
    float* stats    = partials + (NN/64)*128;       // 128
    float* pms      = stats + 128;                  // 2
    float* wepack   = pms + 2;                      // 2*64*8
    float* was2     = wepack + 2*HID*8;             // 2*8

    k_etr<<<G*16, 256, 0, stream>>>(edge_attr, eat);
    k_prep<<<2, 64, 0, stream>>>(gat_We, gat_att, wepack, was2);
    k_encode<<<NN/4, 256, 0, stream>>>(x, emb, group_ids, enc_W, enc_b, hA);
    k_stats_partial<<<NN/64, 256, 0, stream>>>(hA, partials);
    k_stats_final<<<1, 64, 0, stream>>>(partials, bn_g, bn_b, stats);
    k_gine<<<G*29, 256, 0, stream>>>(hA, stats, eat, gine_We, gine_be,
                                     gine_W1, gine_b1, gine_W2, gine_b2, hB);
    // GAT layer 0: hB -> hA
    k_xlxr<<<NN/4, 256, 0, stream>>>(hB, gat_Wl, gat_bl, gat_Wr, gat_br,
                                     gat_att, xlb, xrb, axl, axr);
    k_gat<<<G*8, 256, 0, stream>>>(xlb, xrb, axl, axr, eat, wepack,
                                   was2, gat_bias, hA);
    // GAT layer 1: hA -> hB
    k_xlxr<<<NN/4, 256, 0, stream>>>(hA, gat_Wl + HID*HID, gat_bl + HID,
                                     gat_Wr + HID*HID, gat_br + HID,
                                     gat_att + HID, xlb, xrb, axl, axr);
    k_gat<<<G*8, 256, 0, stream>>>(xlb, xrb, axl, axr, eat, wepack + HID*8,
                                   was2 + 8, gat_bias + HID, hB);
    // pooling + head
    k_pool_score<<<NN/4, 256, 0, stream>>>(hB, pool_W1, pool_b1, pool_w2, scores);
    k_pool_reduce<<<1, 1024, 0, stream>>>(scores, pms);
    k_pool_final<<<G, 64, 0, stream>>>(hB, scores, pms, lin1_W, lin1_b,
                                       lin2_W, lin2_b, out);
}

// Round 13
// 242.545 us; speedup vs baseline: 1.1310x; 1.0663x over previous
//
#include <hip/hip_runtime.h>
#include <math.h>

#define R    116
#define R2   (116*116)
#define G    128
#define NN   (R*G)      // 14848 nodes
#define HID  64
#define EDIM 5
#define INCH 116
#define EMBD 16

__device__ __forceinline__ float waveReduceSum(float v) {
#pragma unroll
    for (int m = 32; m >= 1; m >>= 1) v += __shfl_xor(v, m, 64);
    return v;
}

__device__ __forceinline__ float rlane(float v, int i) {
    return __int_as_float(__builtin_amdgcn_readlane(__float_as_int(v), i));
}

// ---------------- edge-attr transpose: eat[g][j][i][e] = ea[g][i][j][e] -------
__global__ __launch_bounds__(256) void k_etr(
    const float* __restrict__ ea, float* __restrict__ eat) {
    int b = blockIdx.x;
    int g = b >> 4;
    int t = b & 15;
    int i0 = (t >> 2) << 5, j0 = (t & 3) << 5;
    int ni = min(32, R - i0), nj = min(32, R - j0);
    __shared__ float tile[32][165];
    const float* src = ea + ((size_t)(g*R + i0)*R + j0)*EDIM;
    int tot = ni * nj * EDIM;
    for (int idx = threadIdx.x; idx < tot; idx += 256) {
        int ii = idx / (nj*EDIM);
        int rem = idx - ii*(nj*EDIM);
        tile[ii][rem] = src[(size_t)ii*R*EDIM + rem];
    }
    __syncthreads();
    float* dst = eat + ((size_t)(g*R + j0)*R + i0)*EDIM;
    int tot2 = nj * ni * EDIM;
    for (int idx = threadIdx.x; idx < tot2; idx += 256) {
        int jj = idx / (ni*EDIM);
        int rem = idx - jj*(ni*EDIM);     // ii*5 + e
        int ii = rem / EDIM, e = rem - ii*EDIM;
        dst[(size_t)jj*R*EDIM + rem] = tile[ii][jj*EDIM + e];
    }
}

// ---------------- prepack GAT per-channel tables + We@att dots ----------------
__global__ __launch_bounds__(64) void k_prep(
    const float* __restrict__ We, const float* __restrict__ att,
    float* __restrict__ wepack, float* __restrict__ was2) {
    int l = blockIdx.x, c = threadIdx.x;
    const float* Wl = We + l*EDIM*HID;
    const float* al = att + l*HID;
    float g0=Wl[c], g1=Wl[64+c], g2=Wl[128+c], g3=Wl[192+c], g4=Wl[256+c];
    float at = al[c];
    float* wp = wepack + l*HID*8 + c*8;
    wp[0]=g0; wp[1]=g1; wp[2]=g2; wp[3]=g3; wp[4]=g4; wp[5]=at;
    wp[6]=0.f; wp[7]=0.f;
    float p0 = waveReduceSum(g0*at);
    float p1 = waveReduceSum(g1*at);
    float p2 = waveReduceSum(g2*at);
    float p3 = waveReduceSum(g3*at);
    float p4 = waveReduceSum(g4*at);
    if (c == 0) {
        float* ws = was2 + l*8;
        ws[0]=p0; ws[1]=p1; ws[2]=p2; ws[3]=p3; ws[4]=p4;
    }
}

// ---------------- encode: h = relu([x, emb[gid]] @ W + b), 4 nodes/block ------
__global__ __launch_bounds__(256) void k_encode(
    const float* __restrict__ x, const float* __restrict__ emb,
    const int* __restrict__ group_ids,
    const float* __restrict__ W, const float* __restrict__ bvec,
    float* __restrict__ h) {
    int w = threadIdx.x >> 6, lane = threadIdx.x & 63;
    int n = blockIdx.x*4 + w;
    __shared__ float xin[4][136];
    for (int idx = lane; idx < INCH; idx += 64) xin[w][idx] = x[(size_t)n*INCH + idx];
    if (lane < EMBD) xin[w][INCH + lane] = emb[group_ids[n]*EMBD + lane];
    float acc = bvec[lane];
#pragma unroll
    for (int k = 0; k < INCH + EMBD; k += 4) {
        float4 q = *(const float4*)&xin[w][k];
        acc = fmaf(q.x, W[(k  )*HID + lane], acc);
        acc = fmaf(q.y, W[(k+1)*HID + lane], acc);
        acc = fmaf(q.z, W[(k+2)*HID + lane], acc);
        acc = fmaf(q.w, W[(k+3)*HID + lane], acc);
    }
    h[(size_t)n*HID + lane] = fmaxf(acc, 0.f);
}

// ---------------- batchnorm stats (two-stage, deterministic) ----------------
__global__ __launch_bounds__(256) void k_stats_partial(
    const float* __restrict__ h, float* __restrict__ partials) {
    int b = blockIdx.x;
    int tid = threadIdx.x;
    int c = tid & 63, r0 = tid >> 6;
    float s = 0.f, s2 = 0.f;
    int row0 = b*64;
#pragma unroll
    for (int k = 0; k < 16; ++k) {
        float v = h[(size_t)(row0 + r0 + 4*k)*HID + c];
        s += v; s2 += v*v;
    }
    __shared__ float ls[256], l2[256];
    ls[tid] = s; l2[tid] = s2;
    __syncthreads();
    if (tid < 64) {
        s  = ls[tid] + ls[tid+64] + ls[tid+128] + ls[tid+192];
        s2 = l2[tid] + l2[tid+64] + l2[tid+128] + l2[tid+192];
        partials[b*128 + tid]      = s;
        partials[b*128 + 64 + tid] = s2;
    }
}

__global__ __launch_bounds__(64) void k_stats_final(
    const float* __restrict__ partials, const float* __restrict__ gam,
    const float* __restrict__ bet, float* __restrict__ stats) {
    int c = threadIdx.x;
    float s = 0.f, s2 = 0.f;
    for (int b = 0; b < NN/64; ++b) {
        s  += partials[b*128 + c];
        s2 += partials[b*128 + 64 + c];
    }
    float mu  = s / (float)NN;
    float var = s2 / (float)NN - mu*mu;
    float rs  = rsqrtf(var + 1e-5f);
    float sc  = rs * gam[c];
    stats[c]      = sc;
    stats[64 + c] = bet[c] - mu*sc;
}

// ------- GINE + fused xlxr(layer0) tail: wave per dst ------------------------
__global__ __launch_bounds__(256) void k_gine_x(
    const float* __restrict__ h, const float* __restrict__ stats,
    const float* __restrict__ eat,
    const float* __restrict__ We, const float* __restrict__ be,
    const float* __restrict__ W1, const float* __restrict__ b1,
    const float* __restrict__ W2, const float* __restrict__ b2,
    float* __restrict__ hout,
    const float* __restrict__ Wl, const float* __restrict__ bl,
    const float* __restrict__ Wr, const float* __restrict__ br,
    const float* __restrict__ att,
    float* __restrict__ oxl, float* __restrict__ oxr,
    float* __restrict__ oaxl, float* __restrict__ oaxr) {
    int b = blockIdx.x;
    int g = b & (G-1), chunk = b >> 7;     // grid G*29; chunk 0..28
    int tid = threadIdx.x, w = tid >> 6, lane = tid & 63;
    int j = chunk*4 + w;                   // exact cover of 116 dsts
    __shared__ float eac[4][R*8];          // per-wave edge column, 8-padded
    __shared__ float t1s[4][68];
    size_t hbase = (size_t)g*R*HID;
    float scv = stats[lane], shv = stats[64 + lane];
    const float* col = eat + (size_t)(g*R + j)*R*EDIM;
    for (int idx = lane; idx < R*EDIM; idx += 64) {
        int i = idx / EDIM, e = idx - i*EDIM;
        eac[w][i*8 + e] = col[idx];
    }
    float w0=We[lane], w1v=We[64+lane], w2v=We[128+lane],
          w3v=We[192+lane], w4v=We[256+lane], bec=be[lane];
    const float* hg = h + hbase;
    float agg = 0.f;
#pragma unroll 4
    for (int i = 0; i < R; ++i) {
        float4 q = *(const float4*)&eac[w][i*8];     // uniform LDS broadcast
        float q4 = eac[w][i*8 + 4];
        float hv = fmaf(hg[(size_t)i*HID + lane], scv, shv);  // L1-hot global
        float ew = bec;
        ew = fmaf(q.x, w0,  ew); ew = fmaf(q.y, w1v, ew);
        ew = fmaf(q.z, w2v, ew); ew = fmaf(q.w, w3v, ew);
        ew = fmaf(q4,  w4v, ew);
        agg += fmaxf(hv + ew, 0.f);
    }
    float h1 = fmaf(hg[(size_t)j*HID + lane], scv, shv) + agg;
    t1s[w][lane] = h1;                     // same-wave in-order LDS
    float a1 = b1[lane];
#pragma unroll
    for (int k = 0; k < HID; k += 4) {
        float4 tq = *(const float4*)&t1s[w][k];
        a1 = fmaf(tq.x, W1[(k  )*HID + lane], a1);
        a1 = fmaf(tq.y, W1[(k+1)*HID + lane], a1);
        a1 = fmaf(tq.z, W1[(k+2)*HID + lane], a1);
        a1 = fmaf(tq.w, W1[(k+3)*HID + lane], a1);
    }
    t1s[w][lane] = fmaxf(a1, 0.f);
    float a2 = b2[lane];
#pragma unroll
    for (int k = 0; k < HID; k += 4) {
        float4 tq = *(const float4*)&t1s[w][k];
        a2 = fmaf(tq.x, W2[(k  )*HID + lane], a2);
        a2 = fmaf(tq.y, W2[(k+1)*HID + lane], a2);
        a2 = fmaf(tq.z, W2[(k+2)*HID + lane], a2);
        a2 = fmaf(tq.w, W2[(k+3)*HID + lane], a2);
    }
    float hr = fmaxf(a2, 0.f);
    hout[hbase + (size_t)j*HID + lane] = hr;
    // ---- fused xlxr (layer 0) for this row ----
    t1s[w][lane] = hr;
    float aL = bl[lane], aR = br[lane];
#pragma unroll
    for (int k = 0; k < HID; k += 4) {
        float4 q = *(const float4*)&t1s[w][k];
        aL = fmaf(q.x, Wl[(k  )*HID + lane], aL);
        aR = fmaf(q.x, Wr[(k  )*HID + lane], aR);
        aL = fmaf(q.y, Wl[(k+1)*HID + lane], aL);
        aR = fmaf(q.y, Wr[(k+1)*HID + lane], aR);
        aL = fmaf(q.z, Wl[(k+2)*HID + lane], aL);
        aR = fmaf(q.z, Wr[(k+2)*HID + lane], aR);
        aL = fmaf(q.w, Wl[(k+3)*HID + lane], aL);
        aR = fmaf(q.w, Wr[(k+3)*HID + lane], aR);
    }
    oxl[hbase + (size_t)j*HID + lane] = aL;
    oxr[hbase + (size_t)j*HID + lane] = aR;
    float at = att[lane];
    float pL = waveReduceSum(aL * at);
    float pR = waveReduceSum(aR * at);
    if (lane == 0) { oaxl[g*R + j] = pL; oaxr[g*R + j] = pR; }
}

// ------- GAT: 8 waves, pairs {w, w+8}; fused tail (xlxr-next or pool) --------
// MODE 0: tail computes xl/xr/axl/axr for next layer.
// MODE 1: tail computes pool scores.
template<int MODE>
__global__ __launch_bounds__(512) void k_gat_x(
    const float* __restrict__ xl, const float* __restrict__ xr,
    const float* __restrict__ axlg, const float* __restrict__ axrg,
    const float* __restrict__ eat, const float* __restrict__ wepack,
    const float* __restrict__ wasg, const float* __restrict__ bias,
    float* __restrict__ hout,
    const float* __restrict__ WA, const float* __restrict__ bA,
    const float* __restrict__ WB, const float* __restrict__ bB,
    const float* __restrict__ attv,
    float* __restrict__ oxl, float* __restrict__ oxr,
    float* __restrict__ oaxl, float* __restrict__ oaxr,
    float* __restrict__ oscores) {
    int b = blockIdx.x;
    int g = b & (G-1), chunk = b >> 7;     // 8 chunks x 15 dsts
    int j0c = chunk*15, jcnt = min(15, R - j0c);
    int tid = threadIdx.x, w = tid >> 6, lane = tid & 63;
    __shared__ float xls[R][66];           // stride 66: 8B-aligned rows
    __shared__ float tt[8][68];
    size_t hbase = (size_t)g*R*HID;
    for (int idx = tid; idx < R*HID; idx += 512)
        xls[idx>>6][idx&63] = xl[hbase + idx];
    float biasv = bias[lane];
    float wasv0 = wasg[0], wasv1 = wasg[1], wasv2 = wasg[2],
          wasv3 = wasg[3], wasv4 = wasg[4];
    bool vB = lane < (R - 64);
    int rb = vB ? (64 + lane) : lane;      // clamped B-row
    float axA = axlg[g*R + lane];
    float axB = axlg[g*R + rb];
    __syncthreads();

    int jj0 = w, jj1 = w + 8;
    bool act0 = jj0 < jcnt, act1 = jj1 < jcnt;
    int j0 = j0c + (act0 ? jj0 : 0);
    int j1 = j0c + (act1 ? jj1 : 0);
    const float* c0 = eat + (size_t)(g*R + j0)*R*EDIM;
    const float* c1 = eat + (size_t)(g*R + j1)*R*EDIM;
    float e0A[5], e0B[5], e1A[5], e1B[5];
#pragma unroll
    for (int e = 0; e < 5; ++e) {
        e0A[e] = c0[lane*EDIM + e];  e0B[e] = c0[rb*EDIM + e];
        e1A[e] = c1[lane*EDIM + e];  e1B[e] = c1[rb*EDIM + e];
    }
    int xo0 = __builtin_amdgcn_readfirstlane(j0*HID);
    int xo1 = __builtin_amdgcn_readfirstlane(j1*HID);
    const float* xr0 = xr + hbase + xo0;
    const float* xr1 = xr + hbase + xo1;
    float axr0 = axrg[g*R + j0];
    float axr1 = axrg[g*R + j1];
    float acc0A=0.f, acc0B=0.f, acc1A=0.f, acc1B=0.f;
#pragma unroll 4
    for (int c = 0; c < HID; c += 2) {
        float2 xA2 = *(const float2*)&xls[lane][c];
        float2 xB2 = *(const float2*)&xls[rb][c];
        const float* wpa = wepack + c*8;             // uniform -> scalar
        const float* wpb = wepack + (c+1)*8;
        float u0a = xr0[c], u0b = xr0[c+1];          // uniform -> scalar
        float u1a = xr1[c], u1b = xr1[c+1];
        {   // channel c
            float zA = xA2.x + u0a;
            zA = fmaf(e0A[0],wpa[0],zA); zA = fmaf(e0A[1],wpa[1],zA);
            zA = fmaf(e0A[2],wpa[2],zA); zA = fmaf(e0A[3],wpa[3],zA);
            zA = fmaf(e0A[4],wpa[4],zA);
            acc0A = fmaf(__builtin_fabsf(zA), wpa[5], acc0A);
            float zB = xB2.x + u0a;
            zB = fmaf(e0B[0],wpa[0],zB); zB = fmaf(e0B[1],wpa[1],zB);
            zB = fmaf(e0B[2],wpa[2],zB); zB = fmaf(e0B[3],wpa[3],zB);
            zB = fmaf(e0B[4],wpa[4],zB);
            acc0B = fmaf(__builtin_fabsf(zB), wpa[5], acc0B);
            float yA = xA2.x + u1a;
            yA = fmaf(e1A[0],wpa[0],yA); yA = fmaf(e1A[1],wpa[1],yA);
            yA = fmaf(e1A[2],wpa[2],yA); yA = fmaf(e1A[3],wpa[3],yA);
            yA = fmaf(e1A[4],wpa[4],yA);
            acc1A = fmaf(__builtin_fabsf(yA), wpa[5], acc1A);
            float yB = xB2.x + u1a;
            yB = fmaf(e1B[0],wpa[0],yB); yB = fmaf(e1B[1],wpa[1],yB);
            yB = fmaf(e1B[2],wpa[2],yB); yB = fmaf(e1B[3],wpa[3],yB);
            yB = fmaf(e1B[4],wpa[4],yB);
            acc1B = fmaf(__builtin_fabsf(yB), wpa[5], acc1B);
        }
        {   // channel c+1
            float zA = xA2.y + u0b;
            zA = fmaf(e0A[0],wpb[0],zA); zA = fmaf(e0A[1],wpb[1],zA);
            zA = fmaf(e0A[2],wpb[2],zA); zA = fmaf(e0A[3],wpb[3],zA);
            zA = fmaf(e0A[4],wpb[4],zA);
            acc0A = fmaf(__builtin_fabsf(zA), wpb[5], acc0A);
            float zB = xB2.y + u0b;
            zB = fmaf(e0B[0],wpb[0],zB); zB = fmaf(e0B[1],wpb[1],zB);
            zB = fmaf(e0B[2],wpb[2],zB); zB = fmaf(e0B[3],wpb[3],zB);
            zB = fmaf(e0B[4],wpb[4],zB);
            acc0B = fmaf(__builtin_fabsf(zB), wpb[5], acc0B);
            float yA = xA2.y + u1b;
            yA = fmaf(e1A[0],wpb[0],yA); yA = fmaf(e1A[1],wpb[1],yA);
            yA = fmaf(e1A[2],wpb[2],yA); yA = fmaf(e1A[3],wpb[3],yA);
            yA = fmaf(e1A[4],wpb[4],yA);
            acc1A = fmaf(__builtin_fabsf(yA), wpb[5], acc1A);
            float yB = xB2.y + u1b;
            yB = fmaf(e1B[0],wpb[0],yB); yB = fmaf(e1B[1],wpb[1],yB);
            yB = fmaf(e1B[2],wpb[2],yB); yB = fmaf(e1B[3],wpb[3],yB);
            yB = fmaf(e1B[4],wpb[4],yB);
            acc1B = fmaf(__builtin_fabsf(yB), wpb[5], acc1B);
        }
    }
    // linear parts: L = axl + axr + ea . (We@att)
    float L0A = axA + axr0, L0B = axB + axr0;
    L0A = fmaf(e0A[0],wasv0,L0A); L0A = fmaf(e0A[1],wasv1,L0A);
    L0A = fmaf(e0A[2],wasv2,L0A); L0A = fmaf(e0A[3],wasv3,L0A);
    L0A = fmaf(e0A[4],wasv4,L0A);
    L0B = fmaf(e0B[0],wasv0,L0B); L0B = fmaf(e0B[1],wasv1,L0B);
    L0B = fmaf(e0B[2],wasv2,L0B); L0B = fmaf(e0B[3],wasv3,L0B);
    L0B = fmaf(e0B[4],wasv4,L0B);
    float L1A = axA + axr1, L1B = axB + axr1;
    L1A = fmaf(e1A[0],wasv0,L1A); L1A = fmaf(e1A[1],wasv1,L1A);
    L1A = fmaf(e1A[2],wasv2,L1A); L1A = fmaf(e1A[3],wasv3,L1A);
    L1A = fmaf(e1A[4],wasv4,L1A);
    L1B = fmaf(e1B[0],wasv0,L1B); L1B = fmaf(e1B[1],wasv1,L1B);
    L1B = fmaf(e1B[2],wasv2,L1B); L1B = fmaf(e1B[3],wasv3,L1B);
    L1B = fmaf(e1B[4],wasv4,L1B);
    // lrelu(z,0.2) = 0.6z + 0.4|z| => score = 0.6*L + 0.4*acc
    float s0A = fmaf(0.4f, acc0A, 0.6f*L0A);
    float s0B = vB ? fmaf(0.4f, acc0B, 0.6f*L0B) : -1e30f;
    float m0 = fmaxf(s0A, s0B);
#pragma unroll
    for (int k = 32; k >= 1; k >>= 1) m0 = fmaxf(m0, __shfl_xor(m0, k, 64));
    float x0A = __expf(s0A - m0);
    float x0B = vB ? __expf(s0B - m0) : 0.f;
    float sm0 = x0A + x0B;
#pragma unroll
    for (int k = 32; k >= 1; k >>= 1) sm0 += __shfl_xor(sm0, k, 64);
    float inv0 = 1.f / (sm0 + 1e-16f);
    float p0A = x0A * inv0, p0B = x0B * inv0;

    float s1A = fmaf(0.4f, acc1A, 0.6f*L1A);
    float s1B = vB ? fmaf(0.4f, acc1B, 0.6f*L1B) : -1e30f;
    float m1 = fmaxf(s1A, s1B);
#pragma unroll
    for (int k = 32; k >= 1; k >>= 1) m1 = fmaxf(m1, __shfl_xor(m1, k, 64));
    float x1A = __expf(s1A - m1);
    float x1B = vB ? __expf(s1B - m1) : 0.f;
    float sm1 = x1A + x1B;
#pragma unroll
    for (int k = 32; k >= 1; k >>= 1) sm1 += __shfl_xor(sm1, k, 64);
    float inv1 = 1.f / (sm1 + 1e-16f);
    float p1A = x1A * inv1, p1B = x1B * inv1;

    // paired aggregation: readlane broadcasts, shared xls reads
    float o0 = 0.f, o1 = 0.f;
#pragma unroll 8
    for (int i = 0; i < 64; ++i) {
        float xv = xls[i][lane];
        o0 = fmaf(rlane(p0A, i), xv, o0);
        o1 = fmaf(rlane(p1A, i), xv, o1);
    }
#pragma unroll 4
    for (int i = 0; i < R-64; ++i) {
        float xv = xls[64+i][lane];
        o0 = fmaf(rlane(p0B, i), xv, o0);
        o1 = fmaf(rlane(p1B, i), xv, o1);
    }
    float hr0 = fmaxf(o0 + biasv, 0.f);
    float hr1 = fmaxf(o1 + biasv, 0.f);

#pragma unroll
    for (int t = 0; t < 2; ++t) {
        bool act = t ? act1 : act0;
        if (!act) continue;                // wave-uniform
        int j = t ? j1 : j0;
        float hr = t ? hr1 : hr0;
        hout[hbase + (size_t)j*HID + lane] = hr;
        tt[w][lane] = hr;                  // same-wave in-order LDS
        if (MODE == 0) {
            float aL = bA[lane], aR = bB[lane];
#pragma unroll
            for (int k = 0; k < HID; k += 4) {
                float4 q = *(const float4*)&tt[w][k];
                aL = fmaf(q.x, WA[(k  )*HID + lane], aL);
                aR = fmaf(q.x, WB[(k  )*HID + lane], aR);
                aL = fmaf(q.y, WA[(k+1)*HID + lane], aL);
                aR = fmaf(q.y, WB[(k+1)*HID + lane], aR);
                aL = fmaf(q.z, WA[(k+2)*HID + lane], aL);
                aR = fmaf(q.z, WB[(k+2)*HID + lane], aR);
                aL = fmaf(q.w, WA[(k+3)*HID + lane], aL);
                aR = fmaf(q.w, WB[(k+3)*HID + lane], aR);
            }
            oxl[hbase + (size_t)j*HID + lane] = aL;
            oxr[hbase + (size_t)j*HID + lane] = aR;
            float at = attv[lane];
            float pL = waveReduceSum(aL * at);
            float pR = waveReduceSum(aR * at);
            if (lane == 0) { oaxl[g*R + j] = pL; oaxr[g*R + j] = pR; }
        } else {
            float acc = bA[lane];
#pragma unroll
            for (int k = 0; k < HID; k += 4) {
                float4 q = *(const float4*)&tt[w][k];
                acc = fmaf(q.x, WA[(k  )*HID + lane], acc);
                acc = fmaf(q.y, WA[(k+1)*HID + lane], acc);
                acc = fmaf(q.z, WA[(k+2)*HID + lane], acc);
                acc = fmaf(q.w, WA[(k+3)*HID + lane], acc);
            }
            float p = tanhf(acc) * attv[lane];
            p = waveReduceSum(p);
            if (lane == 0) oscores[g*R + j] = p;
        }
    }
}

// ---------------- pooling reduce + head ----------------
__global__ __launch_bounds__(1024) void k_pool_reduce(
    const float* __restrict__ scores, float* __restrict__ ms) {
    __shared__ float red[1024];
    int tid = threadIdx.x;
    float m = -1e30f;
    for (int i = tid; i < NN; i += 1024) m = fmaxf(m, scores[i]);
    red[tid] = m;
    __syncthreads();
    for (int s = 512; s > 0; s >>= 1) {
        if (tid < s) red[tid] = fmaxf(red[tid], red[tid+s]);
        __syncthreads();
    }
    float mx = red[0];
    __syncthreads();
    float sum = 0.f;
    for (int i = tid; i < NN; i += 1024) sum += __expf(scores[i] - mx);
    red[tid] = sum;
    __syncthreads();
    for (int s = 512; s > 0; s >>= 1) {
        if (tid < s) red[tid] += red[tid+s];
        __syncthreads();
    }
    if (tid == 0) { ms[0] = mx; ms[1] = red[0]; }
}

__global__ __launch_bounds__(64) void k_pool_final(
    const float* __restrict__ h, const float* __restrict__ scores,
    const float* __restrict__ ms,
    const float* __restrict__ lin1W, const float* __restrict__ lin1b,
    const float* __restrict__ lin2W, const float* __restrict__ lin2b,
    float* __restrict__ out) {
    int g = blockIdx.x, c = threadIdx.x;
    float mx = ms[0], inv = 1.f / ms[1];
    float pc = 0.f;
    int nb = g*R;
    for (int r = 0; r < R; ++r) {
        float wv = __expf(scores[nb + r] - mx) * inv;
        pc = fmaf(h[(size_t)(nb + r)*HID + c], wv, pc);
    }
    __shared__ float pl[HID];
    __shared__ float t[INCH];
    pl[c] = pc;
    __syncthreads();
    for (int k = c; k < INCH; k += 64) {
        float acc = lin1b[k];
#pragma unroll 8
        for (int q = 0; q < HID; ++q) acc = fmaf(pl[q], lin1W[q*INCH + k], acc);
        t[k] = fmaxf(acc, 0.f);
    }
    __syncthreads();
    if (c < 2) {
        float o = lin2b[c];
        for (int k = 0; k < INCH; ++k) o = fmaf(t[k], lin2W[k*2 + c], o);
        out[g*2 + c] = o;
    }
}

extern "C" void kernel_launch(void* const* d_in, const int* in_sizes, int n_in,
                              void* d_out, int out_size, void* d_ws, size_t ws_size,
                              hipStream_t stream) {
    (void)in_sizes; (void)n_in; (void)out_size; (void)ws_size;
    const float* x        = (const float*)d_in[0];
    const float* edge_attr= (const float*)d_in[1];
    const float* emb      = (const float*)d_in[2];
    const float* enc_W    = (const float*)d_in[3];
    const float* enc_b    = (const float*)d_in[4];
    const float* bn_g     = (const float*)d_in[5];
    const float* bn_b     = (const float*)d_in[6];
    const float* gine_We  = (const float*)d_in[7];
    const float* gine_be  = (const float*)d_in[8];
    const float* gine_W1  = (const float*)d_in[9];
    const float* gine_b1  = (const float*)d_in[10];
    const float* gine_W2  = (const float*)d_in[11];
    const float* gine_b2  = (const float*)d_in[12];
    const float* gat_Wl   = (const float*)d_in[13];
    const float* gat_bl   = (const float*)d_in[14];
    const float* gat_Wr   = (const float*)d_in[15];
    const float* gat_br   = (const float*)d_in[16];
    const float* gat_att  = (const float*)d_in[17];
    const float* gat_We   = (const float*)d_in[18];
    const float* gat_bias = (const float*)d_in[19];
    const float* pool_W1  = (const float*)d_in[20];
    const float* pool_b1  = (const float*)d_in[21];
    const float* pool_w2  = (const float*)d_in[22];
    const float* lin1_W   = (const float*)d_in[23];
    const float* lin1_b   = (const float*)d_in[24];
    const float* lin2_W   = (const float*)d_in[25];
    const float* lin2_b   = (const float*)d_in[26];
    const int*   group_ids= (const int*)d_in[29];
    float* out = (float*)d_out;

    float* w = (float*)d_ws;
    float* eat      = w;                            // R2*G*EDIM
    float* hA       = eat + (size_t)R2*G*EDIM;      // NN*HID each below
    float* hB       = hA + (size_t)NN*HID;
    float* xlA      = hB + (size_t)NN*HID;
    float* xrA      = xlA + (size_t)NN*HID;
    float* xlB      = xrA + (size_t)NN*HID;
    float* xrB      = xlB + (size_t)NN*HID;
    float* axlA     = xrB + (size_t)NN*HID;         // NN each below
    float* axrA     = axlA + NN;
    float* axlB     = axrA + NN;
    float* axrB     = axlB + NN;
    float* scores   = axrB + NN;
    float* partials = scores + NN;                  // 232*128
    float* stats    = partials + (NN/64)*128;       // 128
    float* pms      = stats + 128;                  // 2
    float* wepack   = pms + 2;                      // 2*64*8
    float* was2     = wepack + 2*HID*8;             // 2*8

    k_etr<<<G*16, 256, 0, stream>>>(edge_attr, eat);
    k_prep<<<2, 64, 0, stream>>>(gat_We, gat_att, wepack, was2);
    k_encode<<<NN/4, 256, 0, stream>>>(x, emb, group_ids, enc_W, enc_b, hA);
    k_stats_partial<<<NN/64, 256, 0, stream>>>(hA, partials);
    k_stats_final<<<1, 64, 0, stream>>>(partials, bn_g, bn_b, stats);
    // GINE + xlxr(L0)
    k_gine_x<<<G*29, 256, 0, stream>>>(hA, stats, eat, gine_We, gine_be,
                                       gine_W1, gine_b1, gine_W2, gine_b2, hB,
                                       gat_Wl, gat_bl, gat_Wr, gat_br, gat_att,
                                       xlA, xrA, axlA, axrA);
    // GAT layer 0 (+ xlxr L1): -> hA, set B
    k_gat_x<0><<<G*8, 512, 0, stream>>>(xlA, xrA, axlA, axrA, eat, wepack,
                                        was2, gat_bias, hA,
                                        gat_Wl + HID*HID, gat_bl + HID,
                                        gat_Wr + HID*HID, gat_br + HID,
                                        gat_att + HID,
                                        xlB, xrB, axlB, axrB, scores);
    // GAT layer 1 (+ pool scores): -> hB, scores
    k_gat_x<1><<<G*8, 512, 0, stream>>>(xlB, xrB, axlB, axrB, eat,
                                        wepack + HID*8, was2 + 8,
                                        gat_bias + HID, hB,
                                        pool_W1, pool_b1, pool_W1, pool_b1,
                                        pool_w2,
                                        xlA, xrA, axlA, axrA, scores);
    // pooling + head
    k_pool_reduce<<<1, 1024, 0, stream>>>(scores, pms);
    k_pool_final<<<G, 64, 0, stream>>>(hB, scores, pms, lin1_W, lin1_b,
                                       lin2_W, lin2_b, out);
}